// Round 8
// baseline (282.723 us; speedup 1.0000x reference)
//
#include <hip/hip_runtime.h>

constexpr int Bn = 4, CG = 16, HH = 384, WW = 384;
constexpr int HWSZ = HH * WW;  // 147456
constexpr int COUT = 24;
constexpr int TSX = 32, TSY = 16;  // conv tile

// ---------------------------------------------------------------------------
// Weight transpose: Wt[(ic*9+t)*24 + oc] = Wc[(oc*16+ic)*9 + t]
// ---------------------------------------------------------------------------
__global__ void wtrans_kernel(const float* __restrict__ Wc,
                              float* __restrict__ Wt) {
  int i = blockIdx.x * 256 + threadIdx.x;
  if (i < COUT * CG * 9) {
    int oc = i / (CG * 9), rem = i % (CG * 9);
    Wt[rem * COUT + oc] = Wc[i];
  }
}

// ---------------------------------------------------------------------------
// Conv 3x3 SAME 16->24, 32x16 tile, 2 px/thread. Offsets -> d_out layout
// (conv ch c -> out ch c for c<8, c+2 for c>=8; out ch 8,9 zero).
// Aff channels -> ws planes.
// ---------------------------------------------------------------------------
__global__ __launch_bounds__(256) void conv_kernel(
    const float* __restrict__ g, const float* __restrict__ Wt,
    const float* __restrict__ bc, float* __restrict__ out_off,
    float* __restrict__ affc) {
  __shared__ float lds[CG * 18 * 34];
  int bi = blockIdx.x;
  int bx = (bi % (WW / TSX)) * TSX;
  int by = ((bi / (WW / TSX)) % (HH / TSY)) * TSY;
  int b = bi / ((WW / TSX) * (HH / TSY));
  const float* gb = g + (size_t)b * CG * HWSZ;

  for (int idx = threadIdx.x; idx < CG * 18 * 34; idx += 256) {
    int ic = idx / 612, rem = idx % 612, y = rem / 34, x = rem % 34;
    int gy = by + y - 1, gx = bx + x - 1;
    float v = (gy >= 0 && gy < HH && gx >= 0 && gx < WW)
                  ? gb[ic * HWSZ + gy * WW + gx]
                  : 0.f;
    lds[idx] = v;
  }
  __syncthreads();

  int tx = threadIdx.x & 15, ty = threadIdx.x >> 4;
  float acc0[COUT], acc1[COUT];
#pragma unroll
  for (int oc = 0; oc < COUT; ++oc) {
    float bv = bc[oc];
    acc0[oc] = bv;
    acc1[oc] = bv;
  }

  for (int ic = 0; ic < CG; ++ic) {
    const float* base = lds + ic * 612 + ty * 34 + 2 * tx;
    float vals[3][4];
#pragma unroll
    for (int r = 0; r < 3; ++r) {
      float2 v01 = *(const float2*)(base + r * 34);
      float2 v23 = *(const float2*)(base + r * 34 + 2);
      vals[r][0] = v01.x;
      vals[r][1] = v01.y;
      vals[r][2] = v23.x;
      vals[r][3] = v23.y;
    }
#pragma unroll
    for (int r = 0; r < 3; ++r) {
#pragma unroll
      for (int c3 = 0; c3 < 3; ++c3) {
        float va = vals[r][c3], vb = vals[r][c3 + 1];
        const float* wp = Wt + (ic * 9 + r * 3 + c3) * COUT;
#pragma unroll
        for (int oc = 0; oc < COUT; ++oc) {
          acc0[oc] += va * wp[oc];
          acc1[oc] += vb * wp[oc];
        }
      }
    }
  }

  int p = (by + ty) * WW + bx + 2 * tx;
  float* ob = out_off + (size_t)b * 18 * HWSZ;
#pragma unroll
  for (int c = 0; c < 16; ++c) {
    int c18 = (c < 8) ? c : c + 2;
    *(float2*)(ob + c18 * HWSZ + p) = make_float2(acc0[c], acc1[c]);
  }
  *(float2*)(ob + 8 * HWSZ + p) = make_float2(0.f, 0.f);
  *(float2*)(ob + 9 * HWSZ + p) = make_float2(0.f, 0.f);
  float* ab = affc + (size_t)b * 8 * HWSZ;
#pragma unroll
  for (int c = 0; c < 8; ++c)
    *(float2*)(ab + c * HWSZ + p) = make_float2(acc0[16 + c], acc1[16 + c]);
}

// ---------------------------------------------------------------------------
// offT2: pack the c>=4 offset planes (out ch 10..17) into per-(m,Lp) records
// of 16 contiguous floats: [dy j=0..7 | dx j=0..7], where dy plane = ch
// 10+2cp (sel 0), dx plane = ch 11+2cp (sel 1); record index
// ((b*4+cp)*48+m)*384 + Lp; source element = ch[Lp*384 + 8m + j].
// ---------------------------------------------------------------------------
__global__ __launch_bounds__(256) void offt2_kernel(
    const float* __restrict__ out_off, float* __restrict__ offT2) {
  __shared__ float lds[64][68];
  int bi = blockIdx.x;
  int vt = bi % 6;  bi /= 6;   // m-tile: m0 = vt*8 (64 source cols)
  int lt = bi % 6;  bi /= 6;   // Lp-tile: Lp0 = lt*64
  int pl = bi % 8;             // source plane: out ch 10+pl
  int b = bi / 8;
  int cp = pl >> 1, sel = pl & 1;
  const float* src =
      out_off + ((size_t)b * 18 + 10 + pl) * HWSZ + (lt * 64) * WW + vt * 64;
  int t = threadIdx.x;
#pragma unroll
  for (int i = 0; i < 4; ++i) {
    int flat = i * 1024 + t * 4;
    int row = flat >> 6, col = flat & 63;
    *(float4*)&lds[row][col] = *(const float4*)(src + row * WW + col);
  }
  __syncthreads();
  float* dstb = offT2 + (size_t)(b * 4 + cp) * 48 * 384 * 16;
#pragma unroll
  for (int i = 0; i < 4; ++i) {
    int flat = i * 1024 + t * 4;
    int h = (flat >> 2) & 1;
    int Lpl = (flat >> 3) & 63;
    int ml = flat >> 9;
    float4 v = *(const float4*)&lds[Lpl][8 * ml + 4 * h];
    size_t rec = (size_t)(vt * 8 + ml) * 384 + (lt * 64 + Lpl);
    *(float4*)(dstb + rec * 16 + sel * 8 + 4 * h) = v;
  }
}

// Bilinear sample, zero padding — identical math to the reference.
__device__ __forceinline__ float bilin_zero(const float* __restrict__ img,
                                            float iy, float ix) {
  float y0f = floorf(iy), x0f = floorf(ix);
  float wy1 = iy - y0f, wx1 = ix - x0f;
  int y0 = (int)y0f, x0 = (int)x0f;
  float acc = 0.f;
#pragma unroll
  for (int dy = 0; dy < 2; ++dy) {
    int yc = y0 + dy;
    bool vy = (yc >= 0) && (yc <= HH - 1);
    int yi = min(max(yc, 0), HH - 1);
    float wy = dy ? wy1 : 1.f - wy1;
#pragma unroll
    for (int dx = 0; dx < 2; ++dx) {
      int xc = x0 + dx;
      bool vx = (xc >= 0) && (xc <= WW - 1);
      int xi = min(max(xc, 0), WW - 1);
      float wx = dx ? wx1 : 1.f - wx1;
      float v = img[yi * WW + xi];
      acc += v * (wy * wx) * ((vy && vx) ? 1.f : 0.f);
    }
  }
  return acc;
}

// ---------------------------------------------------------------------------
// cw for c=4..7: lanes along Lp (gathers cluster near (8m+j, 8m+j)).
// fea operands and cw4 results staged through LDS so all global traffic is
// float4-per-run (p runs of 4 at stride 48). Offsets read as 64B records.
// ---------------------------------------------------------------------------
__global__ __launch_bounds__(256) void cw47c_kernel(
    const float* __restrict__ fea, const float* __restrict__ offT2,
    float* __restrict__ cw4) {
  __shared__ float sfea[8][64][5];
  __shared__ float scw[4][64][5];
  int bi = blockIdx.x;
  int Lblk = bi % 6;  bi /= 6;
  int mblk = bi % 12; bi /= 12;
  int a = bi % 8, b = bi / 8;
  int t = threadIdx.x;
  const float* feab = fea + (size_t)b * 8 * HWSZ;
  int p_base = a * 18432 + 48 * (Lblk * 64) + mblk * 4;  // + 48*Lpl

  // Cooperative fea load: 512 float4 runs (8 j x 64 Lpl), 2 per thread.
#pragma unroll
  for (int i = 0; i < 2; ++i) {
    int L = i * 256 + t;
    int j = L >> 6, Lpl = L & 63;
    float4 v = *(const float4*)(feab + (size_t)j * HWSZ + p_base + 48 * Lpl);
    sfea[j][Lpl][0] = v.x;
    sfea[j][Lpl][1] = v.y;
    sfea[j][Lpl][2] = v.z;
    sfea[j][Lpl][3] = v.w;
  }
  __syncthreads();

  int lane = t & 63, wv = t >> 6;
  int m = mblk * 4 + wv;
  int Lp = Lblk * 64 + lane;

  float feaj[8];
#pragma unroll
  for (int j = 0; j < 8; ++j) feaj[j] = sfea[j][lane][wv];

  const float* imgA = feab + (size_t)a * HWSZ;
  float qf = (float)(8 * m);

#pragma unroll
  for (int cp = 0; cp < 4; ++cp) {
    const float* rec =
        offT2 + (((size_t)(b * 4 + cp) * 48 + m) * 384 + Lp) * 16;
    float4 dy0 = *(const float4*)rec;
    float4 dy1 = *(const float4*)(rec + 4);
    float4 dx0 = *(const float4*)(rec + 8);
    float4 dx1 = *(const float4*)(rec + 12);
    float s = 0.f;
    s += feaj[0] * bilin_zero(imgA, dx0.x + qf + 0.f, dy0.x + qf + 0.f);
    s += feaj[1] * bilin_zero(imgA, dx0.y + qf + 1.f, dy0.y + qf + 1.f);
    s += feaj[2] * bilin_zero(imgA, dx0.z + qf + 2.f, dy0.z + qf + 2.f);
    s += feaj[3] * bilin_zero(imgA, dx0.w + qf + 3.f, dy0.w + qf + 3.f);
    s += feaj[4] * bilin_zero(imgA, dx1.x + qf + 4.f, dy1.x + qf + 4.f);
    s += feaj[5] * bilin_zero(imgA, dx1.y + qf + 5.f, dy1.y + qf + 5.f);
    s += feaj[6] * bilin_zero(imgA, dx1.z + qf + 6.f, dy1.z + qf + 6.f);
    s += feaj[7] * bilin_zero(imgA, dx1.w + qf + 7.f, dy1.w + qf + 7.f);
    scw[cp][lane][wv] = s;
  }
  __syncthreads();

  // Cooperative cw4 write: 256 float4 runs (4 cp x 64 Lpl), 1 per thread.
  {
    int cp = t >> 6, Lpl = t & 63;
    float4 v;
    v.x = scw[cp][Lpl][0];
    v.y = scw[cp][Lpl][1];
    v.z = scw[cp][Lpl][2];
    v.w = scw[cp][Lpl][3];
    *(float4*)(cw4 + (size_t)(b * 4 + cp) * HWSZ + p_base + 48 * Lpl) = v;
  }
}

__device__ __forceinline__ float fast_tanh(float x) {
  float ax = fabsf(x);
  float e = __expf(2.f * ax);  // inf for large ax -> t = 1 (correct limit)
  float t = 1.f - 2.f * __builtin_amdgcn_rcpf(e + 1.f);
  return copysignf(t, x);
}

// ---------------------------------------------------------------------------
// Fused cw03 + epilogue, register-slimmed, min 4 waves/SIMD.
// ---------------------------------------------------------------------------
__global__ __launch_bounds__(256, 4) void fused_kernel(
    const float* __restrict__ fea, const float* __restrict__ conf_img,
    const float* __restrict__ out_off, const float* __restrict__ affc,
    const float* __restrict__ cw4, const float* __restrict__ aff_scale,
    float* __restrict__ out_aff) {
  unsigned idx = blockIdx.x * 256u + threadIdx.x;
  unsigned b = idx / (unsigned)HWSZ, p = idx % (unsigned)HWSZ;
  unsigned h = p / (unsigned)WW, w = p % (unsigned)WW;

  const float* feab = fea + (size_t)b * 8 * HWSZ;
  float feaj[8];
#pragma unroll
  for (int j = 0; j < 8; ++j) feaj[j] = feab[j * HWSZ + p];

  unsigned m0 = 8u * p;
  unsigned a = m0 / (unsigned)HWSZ;
  unsigned r0 = m0 - a * (unsigned)HWSZ;
  unsigned hr = r0 / (unsigned)WW;
  const float* imgA = feab + a * HWSZ;
  const float* offb = out_off + (size_t)b * 18 * HWSZ;
  const float* ab = affc + (size_t)b * 8 * HWSZ;
  float cb = (float)hr;

  float av[8];
#pragma unroll
  for (int c = 0; c < 4; ++c) {
    const float* dyp = offb + (2 * c) * HWSZ + r0;
    const float* dxp = offb + (2 * c + 1) * HWSZ + r0;
    float4 dy0 = *(const float4*)dyp;
    float4 dx0 = *(const float4*)dxp;
    float s = 0.f;
    s += feaj[0] * bilin_zero(imgA, dx0.x + cb, dy0.x + cb);
    s += feaj[1] * bilin_zero(imgA, dx0.y + cb, dy0.y + cb);
    s += feaj[2] * bilin_zero(imgA, dx0.z + cb, dy0.z + cb);
    s += feaj[3] * bilin_zero(imgA, dx0.w + cb, dy0.w + cb);
    float4 dy1 = *(const float4*)(dyp + 4);
    float4 dx1 = *(const float4*)(dxp + 4);
    s += feaj[4] * bilin_zero(imgA, dx1.x + cb, dy1.x + cb);
    s += feaj[5] * bilin_zero(imgA, dx1.y + cb, dy1.y + cb);
    s += feaj[6] * bilin_zero(imgA, dx1.z + cb, dy1.z + cb);
    s += feaj[7] * bilin_zero(imgA, dx1.w + cb, dy1.w + cb);
    av[c] = ab[c * HWSZ + p] * s;
  }
#pragma unroll
  for (int c = 4; c < 8; ++c)
    av[c] = ab[c * HWSZ + p] * cw4[((size_t)b * 4 + (c - 4)) * HWSZ + p];

  const float* cimg = conf_img + (size_t)b * HWSZ;
  float invden = __builtin_amdgcn_rcpf(aff_scale[0] + 1e-8f);

  float t[8];
  float asum = 0.f;
#pragma unroll
  for (int c = 0; c < 8; ++c) {
    int chy = (c < 4) ? 2 * c : 2 * c + 2;
    float dy = offb[chy * HWSZ + p];
    float dx = offb[(chy + 1) * HWSZ + p];
    float cf = bilin_zero(cimg, dy + (float)h, dx + (float)w);
    float tv = fast_tanh(av[c]) * invden * cf;
    t[c] = tv;
    asum += fabsf(tv);
  }
  asum += 1e-4f;
  asum = fmaxf(asum, 1.f);
  float inv_asum = __builtin_amdgcn_rcpf(asum);
  float ssum = 0.f;
#pragma unroll
  for (int c = 0; c < 8; ++c) {
    t[c] *= inv_asum;
    ssum += t[c];
  }

  float v9[9];
#pragma unroll
  for (int c = 0; c < 4; ++c) v9[c] = t[c];
  v9[4] = 1.f - ssum;
#pragma unroll
  for (int c = 4; c < 8; ++c) v9[c + 1] = t[c];

  float mx = v9[0];
#pragma unroll
  for (int i = 1; i < 9; ++i) mx = fmaxf(mx, v9[i]);
  float es = 0.f;
#pragma unroll
  for (int i = 0; i < 9; ++i) {
    v9[i] = __expf(v9[i] - mx);
    es += v9[i];
  }
  float inv = __builtin_amdgcn_rcpf(es);
  float* ob = out_aff + (size_t)b * 9 * HWSZ;
#pragma unroll
  for (int i = 0; i < 9; ++i) ob[i * HWSZ + p] = v9[i] * inv;
}

extern "C" void kernel_launch(void* const* d_in, const int* in_sizes, int n_in,
                              void* d_out, int out_size, void* d_ws,
                              size_t ws_size, hipStream_t stream) {
  const float* guidance = (const float*)d_in[0];
  const float* conf_img = (const float*)d_in[1];
  const float* fea = (const float*)d_in[2];
  const float* Wc = (const float*)d_in[3];
  const float* bc = (const float*)d_in[4];
  const float* ascale = (const float*)d_in[5];

  float* out = (float*)d_out;
  float* out_off = out;                           // (4,18,384,384)
  float* out_aff = out + (size_t)Bn * 18 * HWSZ;  // (4,9,384,384) final output
  // offT2 borrows the aff region of d_out (4.72M floats <= 5.31M available);
  // consumed by cw47c before fused_kernel overwrites the region.
  float* offT2 = out_aff;

  float* affc = (float*)d_ws;                     // 4*8*HW floats
  float* cw4 = affc + (size_t)Bn * 8 * HWSZ;      // 4*4*HW floats
  float* Wt = cw4 + (size_t)Bn * 4 * HWSZ;        // 3456 floats

  wtrans_kernel<<<(COUT * CG * 9 + 255) / 256, 256, 0, stream>>>(Wc, Wt);

  int total = Bn * HWSZ;
  conv_kernel<<<Bn * (HH / TSY) * (WW / TSX), 256, 0, stream>>>(guidance, Wt,
                                                                bc, out_off,
                                                                affc);
  offt2_kernel<<<Bn * 8 * 6 * 6, 256, 0, stream>>>(out_off, offT2);
  cw47c_kernel<<<total / 256, 256, 0, stream>>>(fea, offT2, cw4);
  fused_kernel<<<total / 256, 256, 0, stream>>>(fea, conf_img, out_off, affc,
                                                cw4, ascale, out_aff);
}

// Round 9
// 271.326 us; speedup vs baseline: 1.0420x; 1.0420x over previous
//
#include <hip/hip_runtime.h>

constexpr int Bn = 4, CG = 16, HH = 384, WW = 384;
constexpr int HWSZ = HH * WW;  // 147456
constexpr int COUT = 24;
constexpr int TSX = 32, TSY = 16;  // conv tile

// ---------------------------------------------------------------------------
// Weight transpose: Wt[(ic*9+t)*24 + oc] = Wc[(oc*16+ic)*9 + t]
// ---------------------------------------------------------------------------
__global__ void wtrans_kernel(const float* __restrict__ Wc,
                              float* __restrict__ Wt) {
  int i = blockIdx.x * 256 + threadIdx.x;
  if (i < COUT * CG * 9) {
    int oc = i / (CG * 9), rem = i % (CG * 9);
    Wt[rem * COUT + oc] = Wc[i];
  }
}

// ---------------------------------------------------------------------------
// Conv 3x3 SAME 16->24, 32x16 tile, 2 px/thread. Offsets -> d_out layout
// (conv ch c -> out ch c for c<8, c+2 for c>=8; out ch 8,9 zero).
// Aff channels -> ws planes.
// ---------------------------------------------------------------------------
__global__ __launch_bounds__(256) void conv_kernel(
    const float* __restrict__ g, const float* __restrict__ Wt,
    const float* __restrict__ bc, float* __restrict__ out_off,
    float* __restrict__ affc) {
  __shared__ float lds[CG * 18 * 34];
  int bi = blockIdx.x;
  int bx = (bi % (WW / TSX)) * TSX;
  int by = ((bi / (WW / TSX)) % (HH / TSY)) * TSY;
  int b = bi / ((WW / TSX) * (HH / TSY));
  const float* gb = g + (size_t)b * CG * HWSZ;

  for (int idx = threadIdx.x; idx < CG * 18 * 34; idx += 256) {
    int ic = idx / 612, rem = idx % 612, y = rem / 34, x = rem % 34;
    int gy = by + y - 1, gx = bx + x - 1;
    float v = (gy >= 0 && gy < HH && gx >= 0 && gx < WW)
                  ? gb[ic * HWSZ + gy * WW + gx]
                  : 0.f;
    lds[idx] = v;
  }
  __syncthreads();

  int tx = threadIdx.x & 15, ty = threadIdx.x >> 4;
  float acc0[COUT], acc1[COUT];
#pragma unroll
  for (int oc = 0; oc < COUT; ++oc) {
    float bv = bc[oc];
    acc0[oc] = bv;
    acc1[oc] = bv;
  }

  for (int ic = 0; ic < CG; ++ic) {
    const float* base = lds + ic * 612 + ty * 34 + 2 * tx;
    float vals[3][4];
#pragma unroll
    for (int r = 0; r < 3; ++r) {
      float2 v01 = *(const float2*)(base + r * 34);
      float2 v23 = *(const float2*)(base + r * 34 + 2);
      vals[r][0] = v01.x;
      vals[r][1] = v01.y;
      vals[r][2] = v23.x;
      vals[r][3] = v23.y;
    }
#pragma unroll
    for (int r = 0; r < 3; ++r) {
#pragma unroll
      for (int c3 = 0; c3 < 3; ++c3) {
        float va = vals[r][c3], vb = vals[r][c3 + 1];
        const float* wp = Wt + (ic * 9 + r * 3 + c3) * COUT;
#pragma unroll
        for (int oc = 0; oc < COUT; ++oc) {
          acc0[oc] += va * wp[oc];
          acc1[oc] += vb * wp[oc];
        }
      }
    }
  }

  int p = (by + ty) * WW + bx + 2 * tx;
  float* ob = out_off + (size_t)b * 18 * HWSZ;
#pragma unroll
  for (int c = 0; c < 16; ++c) {
    int c18 = (c < 8) ? c : c + 2;
    *(float2*)(ob + c18 * HWSZ + p) = make_float2(acc0[c], acc1[c]);
  }
  *(float2*)(ob + 8 * HWSZ + p) = make_float2(0.f, 0.f);
  *(float2*)(ob + 9 * HWSZ + p) = make_float2(0.f, 0.f);
  float* ab = affc + (size_t)b * 8 * HWSZ;
#pragma unroll
  for (int c = 0; c < 8; ++c)
    *(float2*)(ab + c * HWSZ + p) = make_float2(acc0[16 + c], acc1[16 + c]);
}

// ---------------------------------------------------------------------------
// offT2: pack the c>=4 offset planes (out ch 10..17) into per-(m,Lp) records
// of 16 contiguous floats: [dy j=0..7 | dx j=0..7].
// ---------------------------------------------------------------------------
__global__ __launch_bounds__(256) void offt2_kernel(
    const float* __restrict__ out_off, float* __restrict__ offT2) {
  __shared__ float lds[64][68];
  int bi = blockIdx.x;
  int vt = bi % 6;  bi /= 6;   // m-tile: m0 = vt*8 (64 source cols)
  int lt = bi % 6;  bi /= 6;   // Lp-tile: Lp0 = lt*64
  int pl = bi % 8;             // source plane: out ch 10+pl
  int b = bi / 8;
  int cp = pl >> 1, sel = pl & 1;
  const float* src =
      out_off + ((size_t)b * 18 + 10 + pl) * HWSZ + (lt * 64) * WW + vt * 64;
  int t = threadIdx.x;
#pragma unroll
  for (int i = 0; i < 4; ++i) {
    int flat = i * 1024 + t * 4;
    int row = flat >> 6, col = flat & 63;
    *(float4*)&lds[row][col] = *(const float4*)(src + row * WW + col);
  }
  __syncthreads();
  float* dstb = offT2 + (size_t)(b * 4 + cp) * 48 * 384 * 16;
#pragma unroll
  for (int i = 0; i < 4; ++i) {
    int flat = i * 1024 + t * 4;
    int h = (flat >> 2) & 1;
    int Lpl = (flat >> 3) & 63;
    int ml = flat >> 9;
    float4 v = *(const float4*)&lds[Lpl][8 * ml + 4 * h];
    size_t rec = (size_t)(vt * 8 + ml) * 384 + (lt * 64 + Lpl);
    *(float4*)(dstb + rec * 16 + sel * 8 + 4 * h) = v;
  }
}

// ---------------------------------------------------------------------------
// Bilinear prep: corner indices + weights (validity folded in, exact since
// valid is 0.0/1.0). Consume as v[k]*w[k] summed in corner order 00,01,10,11
// -- identical arithmetic to the reference's bilin accumulation.
// ---------------------------------------------------------------------------
__device__ __forceinline__ void bilin_prep(float iy, float ix,
                                           int* __restrict__ idx,
                                           float* __restrict__ w) {
  float y0f = floorf(iy), x0f = floorf(ix);
  float fy = iy - y0f, fx = ix - x0f;
  int y0 = (int)y0f, x0 = (int)x0f;
  int y1 = y0 + 1, x1 = x0 + 1;
  float vy0 = (y0 >= 0 && y0 <= HH - 1) ? 1.f : 0.f;
  float vy1 = (y1 >= 0 && y1 <= HH - 1) ? 1.f : 0.f;
  float vx0 = (x0 >= 0 && x0 <= WW - 1) ? 1.f : 0.f;
  float vx1 = (x1 >= 0 && x1 <= WW - 1) ? 1.f : 0.f;
  int yi0 = min(max(y0, 0), HH - 1) * WW;
  int yi1 = min(max(y1, 0), HH - 1) * WW;
  int xi0 = min(max(x0, 0), WW - 1);
  int xi1 = min(max(x1, 0), WW - 1);
  idx[0] = yi0 + xi0;
  idx[1] = yi0 + xi1;
  idx[2] = yi1 + xi0;
  idx[3] = yi1 + xi1;
  float wy0 = 1.f - fy, wx0 = 1.f - fx;
  w[0] = (wy0 * wx0) * (vy0 * vx0);
  w[1] = (wy0 * fx) * (vy0 * vx1);
  w[2] = (fy * wx0) * (vy1 * vx0);
  w[3] = (fy * fx) * (vy1 * vx1);
}

// ---------------------------------------------------------------------------
// cw for c=4..7: direct loads (no LDS), packed offT2 records, and the gather
// restructured into a 32-load batch per cp for memory-level parallelism.
// ---------------------------------------------------------------------------
__global__ __launch_bounds__(256, 4) void cw47d_kernel(
    const float* __restrict__ fea, const float* __restrict__ offT2,
    float* __restrict__ cw4) {
  int t = threadIdx.x;
  int lane = t & 63, wv = t >> 6;
  int bi = blockIdx.x;
  int Lblk = bi % 6;  bi /= 6;
  int mblk = bi % 12; bi /= 12;
  int a = bi % 8, b = bi / 8;
  int m = mblk * 4 + wv;
  int Lp = Lblk * 64 + lane;
  int p = a * 18432 + 48 * Lp + m;

  const float* feab = fea + (size_t)b * 8 * HWSZ;
  const float* imgA = feab + (size_t)a * HWSZ;

  float feaj[8];
#pragma unroll
  for (int j = 0; j < 8; ++j) feaj[j] = feab[j * HWSZ + p];

  float qf = (float)(8 * m);

#pragma unroll
  for (int cp = 0; cp < 4; ++cp) {
    const float* rec =
        offT2 + (((size_t)(b * 4 + cp) * 48 + m) * 384 + Lp) * 16;
    float4 dy0 = *(const float4*)rec;
    float4 dy1 = *(const float4*)(rec + 4);
    float4 dx0 = *(const float4*)(rec + 8);
    float4 dx1 = *(const float4*)(rec + 12);
    float dyv[8] = {dy0.x, dy0.y, dy0.z, dy0.w, dy1.x, dy1.y, dy1.z, dy1.w};
    float dxv[8] = {dx0.x, dx0.y, dx0.z, dx0.w, dx1.x, dx1.y, dx1.z, dx1.w};
    float v[8][4], wg[8][4];
#pragma unroll
    for (int j = 0; j < 8; ++j) {
      int id[4];
      bilin_prep(dxv[j] + qf + (float)j, dyv[j] + qf + (float)j, id, wg[j]);
      v[j][0] = imgA[id[0]];
      v[j][1] = imgA[id[1]];
      v[j][2] = imgA[id[2]];
      v[j][3] = imgA[id[3]];
    }
    float s = 0.f;
#pragma unroll
    for (int j = 0; j < 8; ++j) {
      float bv = v[j][0] * wg[j][0] + v[j][1] * wg[j][1] +
                 v[j][2] * wg[j][2] + v[j][3] * wg[j][3];
      s += feaj[j] * bv;
    }
    cw4[((size_t)b * 4 + cp) * HWSZ + p] = s;
  }
}

__device__ __forceinline__ float fast_tanh(float x) {
  float ax = fabsf(x);
  float e = __expf(2.f * ax);  // inf for large ax -> t = 1 (correct limit)
  float t = 1.f - 2.f * __builtin_amdgcn_rcpf(e + 1.f);
  return copysignf(t, x);
}

// ---------------------------------------------------------------------------
// Fused cw03 + epilogue with batched gathers (32 loads in flight per c-block
// and for the conf gather).
// ---------------------------------------------------------------------------
__global__ __launch_bounds__(256, 4) void fused2_kernel(
    const float* __restrict__ fea, const float* __restrict__ conf_img,
    const float* __restrict__ out_off, const float* __restrict__ affc,
    const float* __restrict__ cw4, const float* __restrict__ aff_scale,
    float* __restrict__ out_aff) {
  unsigned idx0 = blockIdx.x * 256u + threadIdx.x;
  unsigned b = idx0 / (unsigned)HWSZ, p = idx0 % (unsigned)HWSZ;
  unsigned h = p / (unsigned)WW, wcol = p % (unsigned)WW;

  const float* feab = fea + (size_t)b * 8 * HWSZ;
  float feaj[8];
#pragma unroll
  for (int j = 0; j < 8; ++j) feaj[j] = feab[j * HWSZ + p];

  unsigned m0 = 8u * p;
  unsigned a = m0 / (unsigned)HWSZ;
  unsigned r0 = m0 - a * (unsigned)HWSZ;
  unsigned hr = r0 / (unsigned)WW;
  const float* imgA = feab + a * HWSZ;
  const float* offb = out_off + (size_t)b * 18 * HWSZ;
  const float* ab = affc + (size_t)b * 8 * HWSZ;
  float cb = (float)hr;

  float av[8];
#pragma unroll
  for (int c = 0; c < 4; ++c) {
    const float* dyp = offb + (2 * c) * HWSZ + r0;
    const float* dxp = offb + (2 * c + 1) * HWSZ + r0;
    float4 dy0 = *(const float4*)dyp, dy1 = *(const float4*)(dyp + 4);
    float4 dx0 = *(const float4*)dxp, dx1 = *(const float4*)(dxp + 4);
    float dyv[8] = {dy0.x, dy0.y, dy0.z, dy0.w, dy1.x, dy1.y, dy1.z, dy1.w};
    float dxv[8] = {dx0.x, dx0.y, dx0.z, dx0.w, dx1.x, dx1.y, dx1.z, dx1.w};
    float v[8][4], wg[8][4];
#pragma unroll
    for (int j = 0; j < 8; ++j) {
      int id[4];
      bilin_prep(dxv[j] + cb, dyv[j] + cb, id, wg[j]);
      v[j][0] = imgA[id[0]];
      v[j][1] = imgA[id[1]];
      v[j][2] = imgA[id[2]];
      v[j][3] = imgA[id[3]];
    }
    float s = 0.f;
#pragma unroll
    for (int j = 0; j < 8; ++j) {
      float bv = v[j][0] * wg[j][0] + v[j][1] * wg[j][1] +
                 v[j][2] * wg[j][2] + v[j][3] * wg[j][3];
      s += feaj[j] * bv;
    }
    av[c] = ab[c * HWSZ + p] * s;
  }
#pragma unroll
  for (int c = 4; c < 8; ++c)
    av[c] = ab[c * HWSZ + p] * cw4[((size_t)b * 4 + (c - 4)) * HWSZ + p];

  // Batched conf gather (8 samples x 4 corners = 32 loads in flight).
  const float* cimg = conf_img + (size_t)b * HWSZ;
  float cf[8];
  {
    float v[8][4], wg[8][4];
#pragma unroll
    for (int c = 0; c < 8; ++c) {
      int chy = (c < 4) ? 2 * c : 2 * c + 2;
      float dy = offb[chy * HWSZ + p];
      float dx = offb[(chy + 1) * HWSZ + p];
      int id[4];
      bilin_prep(dy + (float)h, dx + (float)wcol, id, wg[c]);
      v[c][0] = cimg[id[0]];
      v[c][1] = cimg[id[1]];
      v[c][2] = cimg[id[2]];
      v[c][3] = cimg[id[3]];
    }
#pragma unroll
    for (int c = 0; c < 8; ++c)
      cf[c] = v[c][0] * wg[c][0] + v[c][1] * wg[c][1] + v[c][2] * wg[c][2] +
              v[c][3] * wg[c][3];
  }

  float invden = __builtin_amdgcn_rcpf(aff_scale[0] + 1e-8f);
  float t[8];
  float asum = 0.f;
#pragma unroll
  for (int c = 0; c < 8; ++c) {
    float tv = fast_tanh(av[c]) * invden * cf[c];
    t[c] = tv;
    asum += fabsf(tv);
  }
  asum += 1e-4f;
  asum = fmaxf(asum, 1.f);
  float inv_asum = __builtin_amdgcn_rcpf(asum);
  float ssum = 0.f;
#pragma unroll
  for (int c = 0; c < 8; ++c) {
    t[c] *= inv_asum;
    ssum += t[c];
  }

  float v9[9];
#pragma unroll
  for (int c = 0; c < 4; ++c) v9[c] = t[c];
  v9[4] = 1.f - ssum;
#pragma unroll
  for (int c = 4; c < 8; ++c) v9[c + 1] = t[c];

  float mx = v9[0];
#pragma unroll
  for (int i = 1; i < 9; ++i) mx = fmaxf(mx, v9[i]);
  float es = 0.f;
#pragma unroll
  for (int i = 0; i < 9; ++i) {
    v9[i] = __expf(v9[i] - mx);
    es += v9[i];
  }
  float inv = __builtin_amdgcn_rcpf(es);
  float* ob = out_aff + (size_t)b * 9 * HWSZ;
#pragma unroll
  for (int i = 0; i < 9; ++i) ob[i * HWSZ + p] = v9[i] * inv;
}

extern "C" void kernel_launch(void* const* d_in, const int* in_sizes, int n_in,
                              void* d_out, int out_size, void* d_ws,
                              size_t ws_size, hipStream_t stream) {
  const float* guidance = (const float*)d_in[0];
  const float* conf_img = (const float*)d_in[1];
  const float* fea = (const float*)d_in[2];
  const float* Wc = (const float*)d_in[3];
  const float* bc = (const float*)d_in[4];
  const float* ascale = (const float*)d_in[5];

  float* out = (float*)d_out;
  float* out_off = out;                           // (4,18,384,384)
  float* out_aff = out + (size_t)Bn * 18 * HWSZ;  // (4,9,384,384) final output
  // offT2 borrows the aff region of d_out (4.72M floats <= 5.31M available);
  // consumed by cw47d before fused2_kernel overwrites the region.
  float* offT2 = out_aff;

  float* affc = (float*)d_ws;                     // 4*8*HW floats
  float* cw4 = affc + (size_t)Bn * 8 * HWSZ;      // 4*4*HW floats
  float* Wt = cw4 + (size_t)Bn * 4 * HWSZ;        // 3456 floats

  wtrans_kernel<<<(COUT * CG * 9 + 255) / 256, 256, 0, stream>>>(Wc, Wt);

  int total = Bn * HWSZ;
  conv_kernel<<<Bn * (HH / TSY) * (WW / TSX), 256, 0, stream>>>(guidance, Wt,
                                                                bc, out_off,
                                                                affc);
  offt2_kernel<<<Bn * 8 * 6 * 6, 256, 0, stream>>>(out_off, offT2);
  cw47d_kernel<<<total / 256, 256, 0, stream>>>(fea, offT2, cw4);
  fused2_kernel<<<total / 256, 256, 0, stream>>>(fea, conf_img, out_off, affc,
                                                 cw4, ascale, out_aff);
}

// Round 11
// 265.379 us; speedup vs baseline: 1.0654x; 1.0224x over previous
//
#include <hip/hip_runtime.h>

constexpr int Bn = 4, CG = 16, HH = 384, WW = 384;
constexpr int HWSZ = HH * WW;  // 147456
constexpr int COUT = 24;
constexpr int TSX = 32, TSY = 16;  // conv tile

// ---------------------------------------------------------------------------
// Weight transpose: Wt[(ic*9+t)*24 + oc] = Wc[(oc*16+ic)*9 + t]
// ---------------------------------------------------------------------------
__global__ void wtrans_kernel(const float* __restrict__ Wc,
                              float* __restrict__ Wt) {
  int i = blockIdx.x * 256 + threadIdx.x;
  if (i < COUT * CG * 9) {
    int oc = i / (CG * 9), rem = i % (CG * 9);
    Wt[rem * COUT + oc] = Wc[i];
  }
}

// ---------------------------------------------------------------------------
// Conv 3x3 SAME 16->24, 32x16 tile, 2 px/thread. Offsets -> d_out layout
// (conv ch c -> out ch c for c<8, c+2 for c>=8; out ch 8,9 zero).
// Aff channels -> ws planes.
// ---------------------------------------------------------------------------
__global__ __launch_bounds__(256) void conv_kernel(
    const float* __restrict__ g, const float* __restrict__ Wt,
    const float* __restrict__ bc, float* __restrict__ out_off,
    float* __restrict__ affc) {
  __shared__ float lds[CG * 18 * 34];
  int bi = blockIdx.x;
  int bx = (bi % (WW / TSX)) * TSX;
  int by = ((bi / (WW / TSX)) % (HH / TSY)) * TSY;
  int b = bi / ((WW / TSX) * (HH / TSY));
  const float* gb = g + (size_t)b * CG * HWSZ;

  for (int idx = threadIdx.x; idx < CG * 18 * 34; idx += 256) {
    int ic = idx / 612, rem = idx % 612, y = rem / 34, x = rem % 34;
    int gy = by + y - 1, gx = bx + x - 1;
    float v = (gy >= 0 && gy < HH && gx >= 0 && gx < WW)
                  ? gb[ic * HWSZ + gy * WW + gx]
                  : 0.f;
    lds[idx] = v;
  }
  __syncthreads();

  int tx = threadIdx.x & 15, ty = threadIdx.x >> 4;
  float acc0[COUT], acc1[COUT];
#pragma unroll
  for (int oc = 0; oc < COUT; ++oc) {
    float bv = bc[oc];
    acc0[oc] = bv;
    acc1[oc] = bv;
  }

  for (int ic = 0; ic < CG; ++ic) {
    const float* base = lds + ic * 612 + ty * 34 + 2 * tx;
    float vals[3][4];
#pragma unroll
    for (int r = 0; r < 3; ++r) {
      float2 v01 = *(const float2*)(base + r * 34);
      float2 v23 = *(const float2*)(base + r * 34 + 2);
      vals[r][0] = v01.x;
      vals[r][1] = v01.y;
      vals[r][2] = v23.x;
      vals[r][3] = v23.y;
    }
#pragma unroll
    for (int r = 0; r < 3; ++r) {
#pragma unroll
      for (int c3 = 0; c3 < 3; ++c3) {
        float va = vals[r][c3], vb = vals[r][c3 + 1];
        const float* wp = Wt + (ic * 9 + r * 3 + c3) * COUT;
#pragma unroll
        for (int oc = 0; oc < COUT; ++oc) {
          acc0[oc] += va * wp[oc];
          acc1[oc] += vb * wp[oc];
        }
      }
    }
  }

  int p = (by + ty) * WW + bx + 2 * tx;
  float* ob = out_off + (size_t)b * 18 * HWSZ;
#pragma unroll
  for (int c = 0; c < 16; ++c) {
    int c18 = (c < 8) ? c : c + 2;
    *(float2*)(ob + c18 * HWSZ + p) = make_float2(acc0[c], acc1[c]);
  }
  *(float2*)(ob + 8 * HWSZ + p) = make_float2(0.f, 0.f);
  *(float2*)(ob + 9 * HWSZ + p) = make_float2(0.f, 0.f);
  float* ab = affc + (size_t)b * 8 * HWSZ;
#pragma unroll
  for (int c = 0; c < 8; ++c)
    *(float2*)(ab + c * HWSZ + p) = make_float2(acc0[16 + c], acc1[16 + c]);
}

// ---------------------------------------------------------------------------
// offT3: the c>=4 offset planes (out ch 10..17) as 16 float4 SUBPLANES:
// offT3[((b*16 + cp*4 + q)*48 + m)*384 + Lp] = float4 of
//   q=0: dy j=0..3, q=1: dy j=4..7, q=2: dx j=0..3, q=3: dx j=4..7
// where dy = ch 10+2cp, dx = ch 11+2cp, source elem = ch[Lp*384 + 8m + j].
// cw47e reads these with lane-stride 16B (4 lanes/line).
// ---------------------------------------------------------------------------
__global__ __launch_bounds__(256) void offt3_kernel(
    const float* __restrict__ out_off, float4* __restrict__ offT3) {
  __shared__ float lds[64][68];
  int bi = blockIdx.x;
  int vt = bi % 6;  bi /= 6;   // m-tile: m0 = vt*8
  int lt = bi % 6;  bi /= 6;   // Lp-tile: Lp0 = lt*64
  int pl = bi % 8;             // source plane: out ch 10+pl
  int b = bi / 8;
  int cp = pl >> 1, sel = pl & 1;
  const float* src =
      out_off + ((size_t)b * 18 + 10 + pl) * HWSZ + (lt * 64) * WW + vt * 64;
  int t = threadIdx.x;
#pragma unroll
  for (int i = 0; i < 4; ++i) {
    int flat = i * 1024 + t * 4;
    int row = flat >> 6, col = flat & 63;
    *(float4*)&lds[row][col] = *(const float4*)(src + row * WW + col);
  }
  __syncthreads();
#pragma unroll
  for (int i = 0; i < 4; ++i) {
    int f4 = i * 256 + t;          // 1024 float4s per tile
    int Lpl = f4 & 63;
    int ml = (f4 >> 6) & 7;
    int h = f4 >> 9;               // j-half
    float4 v = *(const float4*)&lds[Lpl][8 * ml + 4 * h];
    int q = sel * 2 + h;
    size_t di = ((size_t)(b * 16 + cp * 4 + q) * 48 + (vt * 8 + ml)) * 384 +
                (lt * 64 + Lpl);
    offT3[di] = v;
  }
}

// ---------------------------------------------------------------------------
// Bilinear prep: corner indices + weights (validity folded in, exact since
// valid is 0.0/1.0). Consume as v[k]*w[k] summed in corner order 00,01,10,11
// -- identical arithmetic to the reference's bilin accumulation.
// ---------------------------------------------------------------------------
__device__ __forceinline__ void bilin_prep(float iy, float ix,
                                           int* __restrict__ idx,
                                           float* __restrict__ w) {
  float y0f = floorf(iy), x0f = floorf(ix);
  float fy = iy - y0f, fx = ix - x0f;
  int y0 = (int)y0f, x0 = (int)x0f;
  int y1 = y0 + 1, x1 = x0 + 1;
  float vy0 = (y0 >= 0 && y0 <= HH - 1) ? 1.f : 0.f;
  float vy1 = (y1 >= 0 && y1 <= HH - 1) ? 1.f : 0.f;
  float vx0 = (x0 >= 0 && x0 <= WW - 1) ? 1.f : 0.f;
  float vx1 = (x1 >= 0 && x1 <= WW - 1) ? 1.f : 0.f;
  int yi0 = min(max(y0, 0), HH - 1) * WW;
  int yi1 = min(max(y1, 0), HH - 1) * WW;
  int xi0 = min(max(x0, 0), WW - 1);
  int xi1 = min(max(x1, 0), WW - 1);
  idx[0] = yi0 + xi0;
  idx[1] = yi0 + xi1;
  idx[2] = yi1 + xi0;
  idx[3] = yi1 + xi1;
  float wy0 = 1.f - fy, wx0 = 1.f - fx;
  w[0] = (wy0 * wx0) * (vy0 * vx0);
  w[1] = (wy0 * fx) * (vy0 * vx1);
  w[2] = (fy * wx0) * (vy1 * vx0);
  w[3] = (fy * fx) * (vy1 * vx1);
}

// ---------------------------------------------------------------------------
// cw for c=4..7: lanes along Lp (gathers cluster near (8m+j, 8m+j)); offsets
// from float4 subplanes (lane-stride 16B); all independent loads hoisted.
// ---------------------------------------------------------------------------
__global__ __launch_bounds__(256, 4) void cw47e_kernel(
    const float* __restrict__ fea, const float4* __restrict__ offT3,
    float* __restrict__ cw4) {
  int t = threadIdx.x;
  int lane = t & 63, wv = t >> 6;
  int bi = blockIdx.x;
  int Lblk = bi % 6;  bi /= 6;
  int mblk = bi % 12; bi /= 12;
  int a = bi % 8, b = bi / 8;
  int m = mblk * 4 + wv;
  int Lp = Lblk * 64 + lane;
  int p = a * 18432 + 48 * Lp + m;

  const float* feab = fea + (size_t)b * 8 * HWSZ;
  const float* imgA = feab + (size_t)a * HWSZ;
  const float4* o3 = offT3 + (size_t)b * 16 * 48 * 384;
  int recoff = m * 384 + Lp;

  float feaj[8];
#pragma unroll
  for (int j = 0; j < 8; ++j) feaj[j] = feab[j * HWSZ + p];

  float qf = (float)(8 * m);

#pragma unroll
  for (int cp = 0; cp < 4; ++cp) {
    float4 dy0 = o3[(cp * 4 + 0) * 18432 + recoff];
    float4 dy1 = o3[(cp * 4 + 1) * 18432 + recoff];
    float4 dx0 = o3[(cp * 4 + 2) * 18432 + recoff];
    float4 dx1 = o3[(cp * 4 + 3) * 18432 + recoff];
    float dyv[8] = {dy0.x, dy0.y, dy0.z, dy0.w, dy1.x, dy1.y, dy1.z, dy1.w};
    float dxv[8] = {dx0.x, dx0.y, dx0.z, dx0.w, dx1.x, dx1.y, dx1.z, dx1.w};
    float v[8][4], wg[8][4];
#pragma unroll
    for (int j = 0; j < 8; ++j) {
      int id[4];
      bilin_prep(dxv[j] + qf + (float)j, dyv[j] + qf + (float)j, id, wg[j]);
      v[j][0] = imgA[id[0]];
      v[j][1] = imgA[id[1]];
      v[j][2] = imgA[id[2]];
      v[j][3] = imgA[id[3]];
    }
    float s = 0.f;
#pragma unroll
    for (int j = 0; j < 8; ++j) {
      float bv = v[j][0] * wg[j][0] + v[j][1] * wg[j][1] +
                 v[j][2] * wg[j][2] + v[j][3] * wg[j][3];
      s += feaj[j] * bv;
    }
    cw4[((size_t)b * 4 + cp) * HWSZ + p] = s;
  }
}

__device__ __forceinline__ float fast_tanh(float x) {
  float ax = fabsf(x);
  float e = __expf(2.f * ax);  // inf for large ax -> t = 1 (correct limit)
  float t = 1.f - 2.f * __builtin_amdgcn_rcpf(e + 1.f);
  return copysignf(t, x);
}

// ---------------------------------------------------------------------------
// Fused cw03 + epilogue with batched gathers.
// ---------------------------------------------------------------------------
__global__ __launch_bounds__(256, 4) void fused2_kernel(
    const float* __restrict__ fea, const float* __restrict__ conf_img,
    const float* __restrict__ out_off, const float* __restrict__ affc,
    const float* __restrict__ cw4, const float* __restrict__ aff_scale,
    float* __restrict__ out_aff) {
  unsigned idx0 = blockIdx.x * 256u + threadIdx.x;
  unsigned b = idx0 / (unsigned)HWSZ, p = idx0 % (unsigned)HWSZ;
  unsigned h = p / (unsigned)WW, wcol = p % (unsigned)WW;

  const float* feab = fea + (size_t)b * 8 * HWSZ;
  float feaj[8];
#pragma unroll
  for (int j = 0; j < 8; ++j) feaj[j] = feab[j * HWSZ + p];

  unsigned m0 = 8u * p;
  unsigned a = m0 / (unsigned)HWSZ;
  unsigned r0 = m0 - a * (unsigned)HWSZ;
  unsigned hr = r0 / (unsigned)WW;
  const float* imgA = feab + a * HWSZ;
  const float* offb = out_off + (size_t)b * 18 * HWSZ;
  const float* ab = affc + (size_t)b * 8 * HWSZ;
  float cb = (float)hr;

  float av[8];
#pragma unroll
  for (int c = 0; c < 4; ++c) {
    const float* dyp = offb + (2 * c) * HWSZ + r0;
    const float* dxp = offb + (2 * c + 1) * HWSZ + r0;
    float4 dy0 = *(const float4*)dyp, dy1 = *(const float4*)(dyp + 4);
    float4 dx0 = *(const float4*)dxp, dx1 = *(const float4*)(dxp + 4);
    float dyv[8] = {dy0.x, dy0.y, dy0.z, dy0.w, dy1.x, dy1.y, dy1.z, dy1.w};
    float dxv[8] = {dx0.x, dx0.y, dx0.z, dx0.w, dx1.x, dx1.y, dx1.z, dx1.w};
    float v[8][4], wg[8][4];
#pragma unroll
    for (int j = 0; j < 8; ++j) {
      int id[4];
      bilin_prep(dxv[j] + cb, dyv[j] + cb, id, wg[j]);
      v[j][0] = imgA[id[0]];
      v[j][1] = imgA[id[1]];
      v[j][2] = imgA[id[2]];
      v[j][3] = imgA[id[3]];
    }
    float s = 0.f;
#pragma unroll
    for (int j = 0; j < 8; ++j) {
      float bv = v[j][0] * wg[j][0] + v[j][1] * wg[j][1] +
                 v[j][2] * wg[j][2] + v[j][3] * wg[j][3];
      s += feaj[j] * bv;
    }
    av[c] = ab[c * HWSZ + p] * s;
  }
#pragma unroll
  for (int c = 4; c < 8; ++c)
    av[c] = ab[c * HWSZ + p] * cw4[((size_t)b * 4 + (c - 4)) * HWSZ + p];

  // Batched conf gather (8 samples x 4 corners = 32 loads in flight).
  const float* cimg = conf_img + (size_t)b * HWSZ;
  float cf[8];
  {
    float v[8][4], wg[8][4];
#pragma unroll
    for (int c = 0; c < 8; ++c) {
      int chy = (c < 4) ? 2 * c : 2 * c + 2;
      float dy = offb[chy * HWSZ + p];
      float dx = offb[(chy + 1) * HWSZ + p];
      int id[4];
      bilin_prep(dy + (float)h, dx + (float)wcol, id, wg[c]);
      v[c][0] = cimg[id[0]];
      v[c][1] = cimg[id[1]];
      v[c][2] = cimg[id[2]];
      v[c][3] = cimg[id[3]];
    }
#pragma unroll
    for (int c = 0; c < 8; ++c)
      cf[c] = v[c][0] * wg[c][0] + v[c][1] * wg[c][1] + v[c][2] * wg[c][2] +
              v[c][3] * wg[c][3];
  }

  float invden = __builtin_amdgcn_rcpf(aff_scale[0] + 1e-8f);
  float t[8];
  float asum = 0.f;
#pragma unroll
  for (int c = 0; c < 8; ++c) {
    float tv = fast_tanh(av[c]) * invden * cf[c];
    t[c] = tv;
    asum += fabsf(tv);
  }
  asum += 1e-4f;
  asum = fmaxf(asum, 1.f);
  float inv_asum = __builtin_amdgcn_rcpf(asum);
  float ssum = 0.f;
#pragma unroll
  for (int c = 0; c < 8; ++c) {
    t[c] *= inv_asum;
    ssum += t[c];
  }

  float v9[9];
#pragma unroll
  for (int c = 0; c < 4; ++c) v9[c] = t[c];
  v9[4] = 1.f - ssum;
#pragma unroll
  for (int c = 4; c < 8; ++c) v9[c + 1] = t[c];

  float mx = v9[0];
#pragma unroll
  for (int i = 1; i < 9; ++i) mx = fmaxf(mx, v9[i]);
  float es = 0.f;
#pragma unroll
  for (int i = 0; i < 9; ++i) {
    v9[i] = __expf(v9[i] - mx);
    es += v9[i];
  }
  float inv = __builtin_amdgcn_rcpf(es);
  float* ob = out_aff + (size_t)b * 9 * HWSZ;
#pragma unroll
  for (int i = 0; i < 9; ++i) ob[i * HWSZ + p] = v9[i] * inv;
}

extern "C" void kernel_launch(void* const* d_in, const int* in_sizes, int n_in,
                              void* d_out, int out_size, void* d_ws,
                              size_t ws_size, hipStream_t stream) {
  const float* guidance = (const float*)d_in[0];
  const float* conf_img = (const float*)d_in[1];
  const float* fea = (const float*)d_in[2];
  const float* Wc = (const float*)d_in[3];
  const float* bc = (const float*)d_in[4];
  const float* ascale = (const float*)d_in[5];

  float* out = (float*)d_out;
  float* out_off = out;                           // (4,18,384,384)
  float* out_aff = out + (size_t)Bn * 18 * HWSZ;  // (4,9,384,384) final output
  // offT3 borrows the aff region of d_out (4.72M floats <= 5.31M available);
  // consumed by cw47e before fused2_kernel overwrites the region. 16B-aligned.
  float4* offT3 = (float4*)out_aff;

  float* affc = (float*)d_ws;                     // 4*8*HW floats
  float* cw4 = affc + (size_t)Bn * 8 * HWSZ;      // 4*4*HW floats
  float* Wt = cw4 + (size_t)Bn * 4 * HWSZ;        // 3456 floats

  wtrans_kernel<<<(COUT * CG * 9 + 255) / 256, 256, 0, stream>>>(Wc, Wt);

  int total = Bn * HWSZ;
  conv_kernel<<<Bn * (HH / TSY) * (WW / TSX), 256, 0, stream>>>(guidance, Wt,
                                                                bc, out_off,
                                                                affc);
  offt3_kernel<<<Bn * 8 * 6 * 6, 256, 0, stream>>>(out_off, offT3);
  cw47e_kernel<<<total / 256, 256, 0, stream>>>(fea, offT3, cw4);
  fused2_kernel<<<total / 256, 256, 0, stream>>>(fea, conf_img, out_off, affc,
                                                 cw4, ascale, out_aff);
}

// Round 13
// 250.522 us; speedup vs baseline: 1.1285x; 1.0593x over previous
//
#include <hip/hip_runtime.h>

constexpr int Bn = 4, CG = 16, HH = 384, WW = 384;
constexpr int HWSZ = HH * WW;  // 147456
constexpr int COUT = 24;
constexpr int TSX = 32, TSY = 16;  // conv tile

// ---------------------------------------------------------------------------
// Weight transpose: Wt[(ic*9+t)*24 + oc] = Wc[(oc*16+ic)*9 + t]
// ---------------------------------------------------------------------------
__global__ void wtrans_kernel(const float* __restrict__ Wc,
                              float* __restrict__ Wt) {
  int i = blockIdx.x * 256 + threadIdx.x;
  if (i < COUT * CG * 9) {
    int oc = i / (CG * 9), rem = i % (CG * 9);
    Wt[rem * COUT + oc] = Wc[i];
  }
}

// ---------------------------------------------------------------------------
// Conv 3x3 SAME 16->24, 32x16 tile, 2 px/thread, ic staged in 2 halves of 8
// (LDS 19.6KB -> 8 blocks/CU cap vs 4 at 39KB). Offsets -> d_out layout
// (conv ch c -> out ch c for c<8, c+2 for c>=8; out ch 8,9 zero).
// Aff channels -> ws planes.
// ---------------------------------------------------------------------------
__global__ __launch_bounds__(256) void conv_kernel(
    const float* __restrict__ g, const float* __restrict__ Wt,
    const float* __restrict__ bc, float* __restrict__ out_off,
    float* __restrict__ affc) {
  __shared__ float lds[8 * 18 * 34];  // 19.6 KB
  int bi = blockIdx.x;
  int bx = (bi % (WW / TSX)) * TSX;
  int by = ((bi / (WW / TSX)) % (HH / TSY)) * TSY;
  int b = bi / ((WW / TSX) * (HH / TSY));
  const float* gb = g + (size_t)b * CG * HWSZ;

  int tx = threadIdx.x & 15, ty = threadIdx.x >> 4;
  float acc0[COUT], acc1[COUT];
#pragma unroll
  for (int oc = 0; oc < COUT; ++oc) {
    float bv = bc[oc];
    acc0[oc] = bv;
    acc1[oc] = bv;
  }

  for (int half = 0; half < 2; ++half) {
    if (half) __syncthreads();
    for (int idx = threadIdx.x; idx < 8 * 18 * 34; idx += 256) {
      int icl = idx / 612, rem = idx % 612, y = rem / 34, x = rem % 34;
      int gy = by + y - 1, gx = bx + x - 1;
      float v = (gy >= 0 && gy < HH && gx >= 0 && gx < WW)
                    ? gb[(half * 8 + icl) * HWSZ + gy * WW + gx]
                    : 0.f;
      lds[idx] = v;
    }
    __syncthreads();

    for (int icl = 0; icl < 8; ++icl) {
      int ic = half * 8 + icl;
      const float* base = lds + icl * 612 + ty * 34 + 2 * tx;
      float vals[3][4];
#pragma unroll
      for (int r = 0; r < 3; ++r) {
        float2 v01 = *(const float2*)(base + r * 34);
        float2 v23 = *(const float2*)(base + r * 34 + 2);
        vals[r][0] = v01.x;
        vals[r][1] = v01.y;
        vals[r][2] = v23.x;
        vals[r][3] = v23.y;
      }
#pragma unroll
      for (int r = 0; r < 3; ++r) {
#pragma unroll
        for (int c3 = 0; c3 < 3; ++c3) {
          float va = vals[r][c3], vb = vals[r][c3 + 1];
          const float* wp = Wt + (ic * 9 + r * 3 + c3) * COUT;
#pragma unroll
          for (int oc = 0; oc < COUT; ++oc) {
            acc0[oc] += va * wp[oc];
            acc1[oc] += vb * wp[oc];
          }
        }
      }
    }
  }

  int p = (by + ty) * WW + bx + 2 * tx;
  float* ob = out_off + (size_t)b * 18 * HWSZ;
#pragma unroll
  for (int c = 0; c < 16; ++c) {
    int c18 = (c < 8) ? c : c + 2;
    *(float2*)(ob + c18 * HWSZ + p) = make_float2(acc0[c], acc1[c]);
  }
  *(float2*)(ob + 8 * HWSZ + p) = make_float2(0.f, 0.f);
  *(float2*)(ob + 9 * HWSZ + p) = make_float2(0.f, 0.f);
  float* ab = affc + (size_t)b * 8 * HWSZ;
#pragma unroll
  for (int c = 0; c < 8; ++c)
    *(float2*)(ab + c * HWSZ + p) = make_float2(acc0[16 + c], acc1[16 + c]);
}

// ---------------------------------------------------------------------------
// offT3: the c>=4 offset planes (out ch 10..17) as 16 float4 SUBPLANES.
// ---------------------------------------------------------------------------
__global__ __launch_bounds__(256) void offt3_kernel(
    const float* __restrict__ out_off, float4* __restrict__ offT3) {
  __shared__ float lds[64][68];
  int bi = blockIdx.x;
  int vt = bi % 6;  bi /= 6;   // m-tile: m0 = vt*8
  int lt = bi % 6;  bi /= 6;   // Lp-tile: Lp0 = lt*64
  int pl = bi % 8;             // source plane: out ch 10+pl
  int b = bi / 8;
  int cp = pl >> 1, sel = pl & 1;
  const float* src =
      out_off + ((size_t)b * 18 + 10 + pl) * HWSZ + (lt * 64) * WW + vt * 64;
  int t = threadIdx.x;
#pragma unroll
  for (int i = 0; i < 4; ++i) {
    int flat = i * 1024 + t * 4;
    int row = flat >> 6, col = flat & 63;
    *(float4*)&lds[row][col] = *(const float4*)(src + row * WW + col);
  }
  __syncthreads();
#pragma unroll
  for (int i = 0; i < 4; ++i) {
    int f4 = i * 256 + t;          // 1024 float4s per tile
    int Lpl = f4 & 63;
    int ml = (f4 >> 6) & 7;
    int h = f4 >> 9;               // j-half
    float4 v = *(const float4*)&lds[Lpl][8 * ml + 4 * h];
    int q = sel * 2 + h;
    size_t di = ((size_t)(b * 16 + cp * 4 + q) * 48 + (vt * 8 + ml)) * 384 +
                (lt * 64 + Lpl);
    offT3[di] = v;
  }
}

// ---------------------------------------------------------------------------
// Bilinear prep: corner indices + weights (validity folded in; exact).
// ---------------------------------------------------------------------------
__device__ __forceinline__ void bilin_prep(float iy, float ix,
                                           int* __restrict__ idx,
                                           float* __restrict__ w) {
  float y0f = floorf(iy), x0f = floorf(ix);
  float fy = iy - y0f, fx = ix - x0f;
  int y0 = (int)y0f, x0 = (int)x0f;
  int y1 = y0 + 1, x1 = x0 + 1;
  float vy0 = (y0 >= 0 && y0 <= HH - 1) ? 1.f : 0.f;
  float vy1 = (y1 >= 0 && y1 <= HH - 1) ? 1.f : 0.f;
  float vx0 = (x0 >= 0 && x0 <= WW - 1) ? 1.f : 0.f;
  float vx1 = (x1 >= 0 && x1 <= WW - 1) ? 1.f : 0.f;
  int yi0 = min(max(y0, 0), HH - 1) * WW;
  int yi1 = min(max(y1, 0), HH - 1) * WW;
  int xi0 = min(max(x0, 0), WW - 1);
  int xi1 = min(max(x1, 0), WW - 1);
  idx[0] = yi0 + xi0;
  idx[1] = yi0 + xi1;
  idx[2] = yi1 + xi0;
  idx[3] = yi1 + xi1;
  float wy0 = 1.f - fy, wx0 = 1.f - fx;
  w[0] = (wy0 * wx0) * (vy0 * vx0);
  w[1] = (wy0 * fx) * (vy0 * vx1);
  w[2] = (fy * wx0) * (vy1 * vx0);
  w[3] = (fy * fx) * (vy1 * vx1);
}

// 16-gather batch: prep 4 samples' addrs -> fence -> 16 loads -> fence ->
// reduce. sched_barrier(0) stops the scheduler from sinking loads into the
// reduction, forcing ~16 loads in flight (VGPR ~90-110, no spill).
__device__ __forceinline__ float gather_batch4(
    const float* __restrict__ img, const float* __restrict__ coef,
    const float* __restrict__ iyv, const float* __restrict__ ixv) {
  int id[4][4];
  float wg[4][4];
#pragma unroll
  for (int jj = 0; jj < 4; ++jj) bilin_prep(iyv[jj], ixv[jj], id[jj], wg[jj]);
  __builtin_amdgcn_sched_barrier(0);
  float v[4][4];
#pragma unroll
  for (int jj = 0; jj < 4; ++jj) {
    v[jj][0] = img[id[jj][0]];
    v[jj][1] = img[id[jj][1]];
    v[jj][2] = img[id[jj][2]];
    v[jj][3] = img[id[jj][3]];
  }
  __builtin_amdgcn_sched_barrier(0);
  float s = 0.f;
#pragma unroll
  for (int jj = 0; jj < 4; ++jj)
    s += coef[jj] * (v[jj][0] * wg[jj][0] + v[jj][1] * wg[jj][1] +
                     v[jj][2] * wg[jj][2] + v[jj][3] * wg[jj][3]);
  return s;
}

// ---------------------------------------------------------------------------
// cw for c=4..7: lanes along Lp (gathers cluster near (8m+j, 8m+j)); offsets
// from float4 subplanes; gathers issued in fenced 16-load batches.
// ---------------------------------------------------------------------------
__global__ __launch_bounds__(256, 4) void cw47f_kernel(
    const float* __restrict__ fea, const float4* __restrict__ offT3,
    float* __restrict__ cw4) {
  int t = threadIdx.x;
  int lane = t & 63, wv = t >> 6;
  int bi = blockIdx.x;
  int Lblk = bi % 6;  bi /= 6;
  int mblk = bi % 12; bi /= 12;
  int a = bi % 8, b = bi / 8;
  int m = mblk * 4 + wv;
  int Lp = Lblk * 64 + lane;
  int p = a * 18432 + 48 * Lp + m;

  const float* feab = fea + (size_t)b * 8 * HWSZ;
  const float* imgA = feab + (size_t)a * HWSZ;
  const float4* o3 = offT3 + (size_t)b * 16 * 48 * 384;
  int recoff = m * 384 + Lp;

  float feaj[8];
#pragma unroll
  for (int j = 0; j < 8; ++j) feaj[j] = feab[j * HWSZ + p];

  float qf = (float)(8 * m);

#pragma unroll
  for (int cp = 0; cp < 4; ++cp) {
    float4 dy0 = o3[(cp * 4 + 0) * 18432 + recoff];
    float4 dy1 = o3[(cp * 4 + 1) * 18432 + recoff];
    float4 dx0 = o3[(cp * 4 + 2) * 18432 + recoff];
    float4 dx1 = o3[(cp * 4 + 3) * 18432 + recoff];
    float iy0[4] = {dx0.x + qf + 0.f, dx0.y + qf + 1.f, dx0.z + qf + 2.f,
                    dx0.w + qf + 3.f};
    float ix0[4] = {dy0.x + qf + 0.f, dy0.y + qf + 1.f, dy0.z + qf + 2.f,
                    dy0.w + qf + 3.f};
    float iy1[4] = {dx1.x + qf + 4.f, dx1.y + qf + 5.f, dx1.z + qf + 6.f,
                    dx1.w + qf + 7.f};
    float ix1[4] = {dy1.x + qf + 4.f, dy1.y + qf + 5.f, dy1.z + qf + 6.f,
                    dy1.w + qf + 7.f};
    float s = gather_batch4(imgA, &feaj[0], iy0, ix0) +
              gather_batch4(imgA, &feaj[4], iy1, ix1);
    cw4[((size_t)b * 4 + cp) * HWSZ + p] = s;
  }
}

__device__ __forceinline__ float fast_tanh(float x) {
  float ax = fabsf(x);
  float e = __expf(2.f * ax);  // inf for large ax -> t = 1 (correct limit)
  float t = 1.f - 2.f * __builtin_amdgcn_rcpf(e + 1.f);
  return copysignf(t, x);
}

// ---------------------------------------------------------------------------
// Fused cw03 + epilogue; all gathers in fenced 16-load batches.
// ---------------------------------------------------------------------------
__global__ __launch_bounds__(256, 4) void fused3_kernel(
    const float* __restrict__ fea, const float* __restrict__ conf_img,
    const float* __restrict__ out_off, const float* __restrict__ affc,
    const float* __restrict__ cw4, const float* __restrict__ aff_scale,
    float* __restrict__ out_aff) {
  unsigned idx0 = blockIdx.x * 256u + threadIdx.x;
  unsigned b = idx0 / (unsigned)HWSZ, p = idx0 % (unsigned)HWSZ;
  unsigned h = p / (unsigned)WW, wcol = p % (unsigned)WW;

  const float* feab = fea + (size_t)b * 8 * HWSZ;
  float feaj[8];
#pragma unroll
  for (int j = 0; j < 8; ++j) feaj[j] = feab[j * HWSZ + p];

  unsigned m0 = 8u * p;
  unsigned a = m0 / (unsigned)HWSZ;
  unsigned r0 = m0 - a * (unsigned)HWSZ;
  unsigned hr = r0 / (unsigned)WW;
  const float* imgA = feab + a * HWSZ;
  const float* offb = out_off + (size_t)b * 18 * HWSZ;
  const float* ab = affc + (size_t)b * 8 * HWSZ;
  float cb = (float)hr;

  float av[8];
#pragma unroll
  for (int c = 0; c < 4; ++c) {
    const float* dyp = offb + (2 * c) * HWSZ + r0;
    const float* dxp = offb + (2 * c + 1) * HWSZ + r0;
    float4 dy0 = *(const float4*)dyp, dy1 = *(const float4*)(dyp + 4);
    float4 dx0 = *(const float4*)dxp, dx1 = *(const float4*)(dxp + 4);
    float iy0[4] = {dx0.x + cb, dx0.y + cb, dx0.z + cb, dx0.w + cb};
    float ix0[4] = {dy0.x + cb, dy0.y + cb, dy0.z + cb, dy0.w + cb};
    float iy1[4] = {dx1.x + cb, dx1.y + cb, dx1.z + cb, dx1.w + cb};
    float ix1[4] = {dy1.x + cb, dy1.y + cb, dy1.z + cb, dy1.w + cb};
    float s = gather_batch4(imgA, &feaj[0], iy0, ix0) +
              gather_batch4(imgA, &feaj[4], iy1, ix1);
    av[c] = ab[c * HWSZ + p] * s;
  }
#pragma unroll
  for (int c = 4; c < 8; ++c)
    av[c] = ab[c * HWSZ + p] * cw4[((size_t)b * 4 + (c - 4)) * HWSZ + p];

  // Conf gather: two fenced 16-load batches (weights applied per-corner,
  // then coef=1 per-sample; arithmetic matches reference order).
  const float* cimg = conf_img + (size_t)b * HWSZ;
  float cf[8];
  {
#pragma unroll
    for (int g4 = 0; g4 < 2; ++g4) {
      int id[4][4];
      float wg[4][4];
#pragma unroll
      for (int cc = 0; cc < 4; ++cc) {
        int c = g4 * 4 + cc;
        int chy = (c < 4) ? 2 * c : 2 * c + 2;
        float dy = offb[chy * HWSZ + p];
        float dx = offb[(chy + 1) * HWSZ + p];
        bilin_prep(dy + (float)h, dx + (float)wcol, id[cc], wg[cc]);
      }
      __builtin_amdgcn_sched_barrier(0);
      float v[4][4];
#pragma unroll
      for (int cc = 0; cc < 4; ++cc) {
        v[cc][0] = cimg[id[cc][0]];
        v[cc][1] = cimg[id[cc][1]];
        v[cc][2] = cimg[id[cc][2]];
        v[cc][3] = cimg[id[cc][3]];
      }
      __builtin_amdgcn_sched_barrier(0);
#pragma unroll
      for (int cc = 0; cc < 4; ++cc)
        cf[g4 * 4 + cc] = v[cc][0] * wg[cc][0] + v[cc][1] * wg[cc][1] +
                          v[cc][2] * wg[cc][2] + v[cc][3] * wg[cc][3];
    }
  }

  float invden = __builtin_amdgcn_rcpf(aff_scale[0] + 1e-8f);
  float t[8];
  float asum = 0.f;
#pragma unroll
  for (int c = 0; c < 8; ++c) {
    float tv = fast_tanh(av[c]) * invden * cf[c];
    t[c] = tv;
    asum += fabsf(tv);
  }
  asum += 1e-4f;
  asum = fmaxf(asum, 1.f);
  float inv_asum = __builtin_amdgcn_rcpf(asum);
  float ssum = 0.f;
#pragma unroll
  for (int c = 0; c < 8; ++c) {
    t[c] *= inv_asum;
    ssum += t[c];
  }

  float v9[9];
#pragma unroll
  for (int c = 0; c < 4; ++c) v9[c] = t[c];
  v9[4] = 1.f - ssum;
#pragma unroll
  for (int c = 4; c < 8; ++c) v9[c + 1] = t[c];

  float mx = v9[0];
#pragma unroll
  for (int i = 1; i < 9; ++i) mx = fmaxf(mx, v9[i]);
  float es = 0.f;
#pragma unroll
  for (int i = 0; i < 9; ++i) {
    v9[i] = __expf(v9[i] - mx);
    es += v9[i];
  }
  float inv = __builtin_amdgcn_rcpf(es);
  float* ob = out_aff + (size_t)b * 9 * HWSZ;
#pragma unroll
  for (int i = 0; i < 9; ++i) ob[i * HWSZ + p] = v9[i] * inv;
}

extern "C" void kernel_launch(void* const* d_in, const int* in_sizes, int n_in,
                              void* d_out, int out_size, void* d_ws,
                              size_t ws_size, hipStream_t stream) {
  const float* guidance = (const float*)d_in[0];
  const float* conf_img = (const float*)d_in[1];
  const float* fea = (const float*)d_in[2];
  const float* Wc = (const float*)d_in[3];
  const float* bc = (const float*)d_in[4];
  const float* ascale = (const float*)d_in[5];

  float* out = (float*)d_out;
  float* out_off = out;                           // (4,18,384,384)
  float* out_aff = out + (size_t)Bn * 18 * HWSZ;  // (4,9,384,384) final output
  // offT3 borrows the aff region of d_out; consumed by cw47f before fused3
  // overwrites the region. 16B-aligned.
  float4* offT3 = (float4*)out_aff;

  float* affc = (float*)d_ws;                     // 4*8*HW floats
  float* cw4 = affc + (size_t)Bn * 8 * HWSZ;      // 4*4*HW floats
  float* Wt = cw4 + (size_t)Bn * 4 * HWSZ;        // 3456 floats

  wtrans_kernel<<<(COUT * CG * 9 + 255) / 256, 256, 0, stream>>>(Wc, Wt);

  int total = Bn * HWSZ;
  conv_kernel<<<Bn * (HH / TSY) * (WW / TSX), 256, 0, stream>>>(guidance, Wt,
                                                                bc, out_off,
                                                                affc);
  offt3_kernel<<<Bn * 8 * 6 * 6, 256, 0, stream>>>(out_off, offT3);
  cw47f_kernel<<<total / 256, 256, 0, stream>>>(fea, offT3, cw4);
  fused3_kernel<<<total / 256, 256, 0, stream>>>(fea, conf_img, out_off, affc,
                                                 cw4, ascale, out_aff);
}

// Round 14
// 201.177 us; speedup vs baseline: 1.4053x; 1.2453x over previous
//
#include <hip/hip_runtime.h>

constexpr int Bn = 4, CG = 16, HH = 384, WW = 384;
constexpr int HWSZ = HH * WW;  // 147456
constexpr int COUT = 24;
constexpr int TSX = 32, TSY = 16;  // conv tile

// ---------------------------------------------------------------------------
// Weight transpose: Wt[(ic*9+t)*24 + oc] = Wc[(oc*16+ic)*9 + t]
// ---------------------------------------------------------------------------
__global__ void wtrans_kernel(const float* __restrict__ Wc,
                              float* __restrict__ Wt) {
  int i = blockIdx.x * 256 + threadIdx.x;
  if (i < COUT * CG * 9) {
    int oc = i / (CG * 9), rem = i % (CG * 9);
    Wt[rem * COUT + oc] = Wc[i];
  }
}

// ---------------------------------------------------------------------------
// Conv 3x3 SAME 16->24, 32x16 tile, 2 px/thread, ic staged in 2 halves of 8.
// Offsets -> d_out layout (conv ch c -> out ch c for c<8, c+2 for c>=8;
// out ch 8,9 zero). Aff channels -> ws planes. NEW: conv ch 8..15 (the c>=4
// offsets) are ALSO written directly as offT3 float4-subplane records,
// replacing the separate offt3 transpose kernel:
//   float idx = (((b*16 + cp*4 + q)*48 + m)*384 + Lp)*4 + (j&3)
//   cp=pl>>1, sel=pl&1, q=sel*2+(j>>2); pixel (Lp, 8m+j); value=conv ch 8+pl.
// ---------------------------------------------------------------------------
__global__ __launch_bounds__(256) void conv_kernel(
    const float* __restrict__ g, const float* __restrict__ Wt,
    const float* __restrict__ bc, float* __restrict__ out_off,
    float* __restrict__ affc, float* __restrict__ offT3f) {
  __shared__ float lds[8 * 18 * 34];  // 19.6 KB
  int bi = blockIdx.x;
  int bx = (bi % (WW / TSX)) * TSX;
  int by = ((bi / (WW / TSX)) % (HH / TSY)) * TSY;
  int b = bi / ((WW / TSX) * (HH / TSY));
  const float* gb = g + (size_t)b * CG * HWSZ;

  int tx = threadIdx.x & 15, ty = threadIdx.x >> 4;
  float acc0[COUT], acc1[COUT];
#pragma unroll
  for (int oc = 0; oc < COUT; ++oc) {
    float bv = bc[oc];
    acc0[oc] = bv;
    acc1[oc] = bv;
  }

  for (int half = 0; half < 2; ++half) {
    if (half) __syncthreads();
    for (int idx = threadIdx.x; idx < 8 * 18 * 34; idx += 256) {
      int icl = idx / 612, rem = idx % 612, y = rem / 34, x = rem % 34;
      int gy = by + y - 1, gx = bx + x - 1;
      float v = (gy >= 0 && gy < HH && gx >= 0 && gx < WW)
                    ? gb[(half * 8 + icl) * HWSZ + gy * WW + gx]
                    : 0.f;
      lds[idx] = v;
    }
    __syncthreads();

    for (int icl = 0; icl < 8; ++icl) {
      int ic = half * 8 + icl;
      const float* base = lds + icl * 612 + ty * 34 + 2 * tx;
      float vals[3][4];
#pragma unroll
      for (int r = 0; r < 3; ++r) {
        float2 v01 = *(const float2*)(base + r * 34);
        float2 v23 = *(const float2*)(base + r * 34 + 2);
        vals[r][0] = v01.x;
        vals[r][1] = v01.y;
        vals[r][2] = v23.x;
        vals[r][3] = v23.y;
      }
#pragma unroll
      for (int r = 0; r < 3; ++r) {
#pragma unroll
        for (int c3 = 0; c3 < 3; ++c3) {
          float va = vals[r][c3], vb = vals[r][c3 + 1];
          const float* wp = Wt + (ic * 9 + r * 3 + c3) * COUT;
#pragma unroll
          for (int oc = 0; oc < COUT; ++oc) {
            acc0[oc] += va * wp[oc];
            acc1[oc] += vb * wp[oc];
          }
        }
      }
    }
  }

  int p = (by + ty) * WW + bx + 2 * tx;
  float* ob = out_off + (size_t)b * 18 * HWSZ;
#pragma unroll
  for (int c = 0; c < 16; ++c) {
    int c18 = (c < 8) ? c : c + 2;
    *(float2*)(ob + c18 * HWSZ + p) = make_float2(acc0[c], acc1[c]);
  }
  *(float2*)(ob + 8 * HWSZ + p) = make_float2(0.f, 0.f);
  *(float2*)(ob + 9 * HWSZ + p) = make_float2(0.f, 0.f);
  float* ab = affc + (size_t)b * 8 * HWSZ;
#pragma unroll
  for (int c = 0; c < 8; ++c)
    *(float2*)(ab + c * HWSZ + p) = make_float2(acc0[16 + c], acc1[16 + c]);

  // Fused offT3 subplane stores (replaces offt3_kernel).
  {
    int X0 = bx + 2 * tx;
    int m = X0 >> 3, j = X0 & 7;  // j even -> j&3 in {0,2}, float2 ok
    int Lp = by + ty;
    float* o3b = offT3f + (size_t)b * 16 * 48 * 384 * 4;
#pragma unroll
    for (int pl = 0; pl < 8; ++pl) {
      int cp = pl >> 1, sel = pl & 1;
      int q = sel * 2 + (j >> 2);
      size_t di = ((size_t)(cp * 4 + q) * 48 + m) * 384 + Lp;
      *(float2*)(o3b + di * 4 + (j & 3)) =
          make_float2(acc0[8 + pl], acc1[8 + pl]);
    }
  }
}

// ---------------------------------------------------------------------------
// Bilinear sample, zero padding — identical math to the reference (fallback
// and fused3 path).
// ---------------------------------------------------------------------------
__device__ __forceinline__ float bilin_zero(const float* __restrict__ img,
                                            float iy, float ix) {
  float y0f = floorf(iy), x0f = floorf(ix);
  float wy1 = iy - y0f, wx1 = ix - x0f;
  int y0 = (int)y0f, x0 = (int)x0f;
  float acc = 0.f;
#pragma unroll
  for (int dy = 0; dy < 2; ++dy) {
    int yc = y0 + dy;
    bool vy = (yc >= 0) && (yc <= HH - 1);
    int yi = min(max(yc, 0), HH - 1);
    float wy = dy ? wy1 : 1.f - wy1;
#pragma unroll
    for (int dx = 0; dx < 2; ++dx) {
      int xc = x0 + dx;
      bool vx = (xc >= 0) && (xc <= WW - 1);
      int xi = min(max(xc, 0), WW - 1);
      float wx = dx ? wx1 : 1.f - wx1;
      float v = img[yi * WW + xi];
      acc += v * (wy * wx) * ((vy && vx) ? 1.f : 0.f);
    }
  }
  return acc;
}

__device__ __forceinline__ void bilin_prep(float iy, float ix,
                                           int* __restrict__ idx,
                                           float* __restrict__ w) {
  float y0f = floorf(iy), x0f = floorf(ix);
  float fy = iy - y0f, fx = ix - x0f;
  int y0 = (int)y0f, x0 = (int)x0f;
  int y1 = y0 + 1, x1 = x0 + 1;
  float vy0 = (y0 >= 0 && y0 <= HH - 1) ? 1.f : 0.f;
  float vy1 = (y1 >= 0 && y1 <= HH - 1) ? 1.f : 0.f;
  float vx0 = (x0 >= 0 && x0 <= WW - 1) ? 1.f : 0.f;
  float vx1 = (x1 >= 0 && x1 <= WW - 1) ? 1.f : 0.f;
  int yi0 = min(max(y0, 0), HH - 1) * WW;
  int yi1 = min(max(y1, 0), HH - 1) * WW;
  int xi0 = min(max(x0, 0), WW - 1);
  int xi1 = min(max(x1, 0), WW - 1);
  idx[0] = yi0 + xi0;
  idx[1] = yi0 + xi1;
  idx[2] = yi1 + xi0;
  idx[3] = yi1 + xi1;
  float wy0 = 1.f - fy, wx0 = 1.f - fx;
  w[0] = (wy0 * wx0) * (vy0 * vx0);
  w[1] = (wy0 * fx) * (vy0 * vx1);
  w[2] = (fy * wx0) * (vy1 * vx0);
  w[3] = (fy * fx) * (vy1 * vx1);
}

__device__ __forceinline__ float gather_batch4(
    const float* __restrict__ img, const float* __restrict__ coef,
    const float* __restrict__ iyv, const float* __restrict__ ixv) {
  int id[4][4];
  float wg[4][4];
#pragma unroll
  for (int jj = 0; jj < 4; ++jj) bilin_prep(iyv[jj], ixv[jj], id[jj], wg[jj]);
  __builtin_amdgcn_sched_barrier(0);
  float v[4][4];
#pragma unroll
  for (int jj = 0; jj < 4; ++jj) {
    v[jj][0] = img[id[jj][0]];
    v[jj][1] = img[id[jj][1]];
    v[jj][2] = img[id[jj][2]];
    v[jj][3] = img[id[jj][3]];
  }
  __builtin_amdgcn_sched_barrier(0);
  float s = 0.f;
#pragma unroll
  for (int jj = 0; jj < 4; ++jj)
    s += coef[jj] * (v[jj][0] * wg[jj][0] + v[jj][1] * wg[jj][1] +
                     v[jj][2] * wg[jj][2] + v[jj][3] * wg[jj][3]);
  return s;
}

// ---------------------------------------------------------------------------
// cw for c=4..7 with LDS-staged 64x64 image patch. Gather center 8m+j is
// lane-uniform, so all 64 lanes sample within +-few px of the same diagonal
// point -> patch rows/cols [R0, R0+63] with R0 = clamp(32*mblk-12, 0, 320)
// covers the typical case; out-of-patch samples take the exec-masked global
// fallback (identical math).
// ---------------------------------------------------------------------------
__global__ __launch_bounds__(256, 4) void cw47g_kernel(
    const float* __restrict__ fea, const float4* __restrict__ offT3,
    float* __restrict__ cw4) {
  __shared__ float patch[64][68];
  int t = threadIdx.x;
  int lane = t & 63, wv = t >> 6;
  int bi = blockIdx.x;
  int Lblk = bi % 6;  bi /= 6;
  int mblk = bi % 12; bi /= 12;
  int a = bi % 8, b = bi / 8;
  int m = mblk * 4 + wv;
  int Lp = Lblk * 64 + lane;
  int p = a * 18432 + 48 * Lp + m;

  const float* feab = fea + (size_t)b * 8 * HWSZ;
  const float* imgA = feab + (size_t)a * HWSZ;

  int R0 = 32 * mblk - 12;
  R0 = (R0 < 0) ? 0 : (R0 > 320 ? 320 : R0);

  // Stage the 64x64 patch (rows/cols R0..R0+63), coalesced float4.
  {
    int row = t >> 4, colq = t & 15;
#pragma unroll
    for (int pass = 0; pass < 4; ++pass) {
      int r = pass * 16 + row;
      float4 v = *(const float4*)(imgA + (R0 + r) * WW + R0 + 4 * colq);
      *(float4*)&patch[r][4 * colq] = v;
    }
  }
  __syncthreads();

  float feaj[8];
#pragma unroll
  for (int j = 0; j < 8; ++j) feaj[j] = feab[j * HWSZ + p];

  const float4* o3 = offT3 + (size_t)b * 16 * 48 * 384;
  int recoff = m * 384 + Lp;
  float qf = (float)(8 * m);

#pragma unroll
  for (int cp = 0; cp < 4; ++cp) {
    float4 dy0 = o3[(cp * 4 + 0) * 18432 + recoff];
    float4 dy1 = o3[(cp * 4 + 1) * 18432 + recoff];
    float4 dx0 = o3[(cp * 4 + 2) * 18432 + recoff];
    float4 dx1 = o3[(cp * 4 + 3) * 18432 + recoff];
    float dyv[8] = {dy0.x, dy0.y, dy0.z, dy0.w, dy1.x, dy1.y, dy1.z, dy1.w};
    float dxv[8] = {dx0.x, dx0.y, dx0.z, dx0.w, dx1.x, dx1.y, dx1.z, dx1.w};
    float s = 0.f;
#pragma unroll
    for (int j = 0; j < 8; ++j) {
      float iy = dxv[j] + qf + (float)j;  // y coordinate
      float ix = dyv[j] + qf + (float)j;  // x coordinate
      float y0f = floorf(iy), x0f = floorf(ix);
      int y0 = (int)y0f, x0 = (int)x0f;
      float fy = iy - y0f, fx = ix - x0f;
      float bv;
      if (y0 >= R0 && y0 <= R0 + 62 && x0 >= R0 && x0 <= R0 + 62) {
        int ry = y0 - R0, rx = x0 - R0;
        float v00 = patch[ry][rx], v01 = patch[ry][rx + 1];
        float v10 = patch[ry + 1][rx], v11 = patch[ry + 1][rx + 1];
        float wy0 = 1.f - fy, wx0 = 1.f - fx;
        bv = v00 * (wy0 * wx0) + v01 * (wy0 * fx) + v10 * (fy * wx0) +
             v11 * (fy * fx);
      } else {
        bv = bilin_zero(imgA, iy, ix);
      }
      s += feaj[j] * bv;
    }
    cw4[((size_t)b * 4 + cp) * HWSZ + p] = s;
  }
}

__device__ __forceinline__ float fast_tanh(float x) {
  float ax = fabsf(x);
  float e = __expf(2.f * ax);  // inf for large ax -> t = 1 (correct limit)
  float t = 1.f - 2.f * __builtin_amdgcn_rcpf(e + 1.f);
  return copysignf(t, x);
}

// ---------------------------------------------------------------------------
// Fused cw03 + epilogue (unchanged from round 13).
// ---------------------------------------------------------------------------
__global__ __launch_bounds__(256, 4) void fused3_kernel(
    const float* __restrict__ fea, const float* __restrict__ conf_img,
    const float* __restrict__ out_off, const float* __restrict__ affc,
    const float* __restrict__ cw4, const float* __restrict__ aff_scale,
    float* __restrict__ out_aff) {
  unsigned idx0 = blockIdx.x * 256u + threadIdx.x;
  unsigned b = idx0 / (unsigned)HWSZ, p = idx0 % (unsigned)HWSZ;
  unsigned h = p / (unsigned)WW, wcol = p % (unsigned)WW;

  const float* feab = fea + (size_t)b * 8 * HWSZ;
  float feaj[8];
#pragma unroll
  for (int j = 0; j < 8; ++j) feaj[j] = feab[j * HWSZ + p];

  unsigned m0 = 8u * p;
  unsigned a = m0 / (unsigned)HWSZ;
  unsigned r0 = m0 - a * (unsigned)HWSZ;
  unsigned hr = r0 / (unsigned)WW;
  const float* imgA = feab + a * HWSZ;
  const float* offb = out_off + (size_t)b * 18 * HWSZ;
  const float* ab = affc + (size_t)b * 8 * HWSZ;
  float cb = (float)hr;

  float av[8];
#pragma unroll
  for (int c = 0; c < 4; ++c) {
    const float* dyp = offb + (2 * c) * HWSZ + r0;
    const float* dxp = offb + (2 * c + 1) * HWSZ + r0;
    float4 dy0 = *(const float4*)dyp, dy1 = *(const float4*)(dyp + 4);
    float4 dx0 = *(const float4*)dxp, dx1 = *(const float4*)(dxp + 4);
    float iy0[4] = {dx0.x + cb, dx0.y + cb, dx0.z + cb, dx0.w + cb};
    float ix0[4] = {dy0.x + cb, dy0.y + cb, dy0.z + cb, dy0.w + cb};
    float iy1[4] = {dx1.x + cb, dx1.y + cb, dx1.z + cb, dx1.w + cb};
    float ix1[4] = {dy1.x + cb, dy1.y + cb, dy1.z + cb, dy1.w + cb};
    float s = gather_batch4(imgA, &feaj[0], iy0, ix0) +
              gather_batch4(imgA, &feaj[4], iy1, ix1);
    av[c] = ab[c * HWSZ + p] * s;
  }
#pragma unroll
  for (int c = 4; c < 8; ++c)
    av[c] = ab[c * HWSZ + p] * cw4[((size_t)b * 4 + (c - 4)) * HWSZ + p];

  const float* cimg = conf_img + (size_t)b * HWSZ;
  float cf[8];
  {
#pragma unroll
    for (int g4 = 0; g4 < 2; ++g4) {
      int id[4][4];
      float wg[4][4];
#pragma unroll
      for (int cc = 0; cc < 4; ++cc) {
        int c = g4 * 4 + cc;
        int chy = (c < 4) ? 2 * c : 2 * c + 2;
        float dy = offb[chy * HWSZ + p];
        float dx = offb[(chy + 1) * HWSZ + p];
        bilin_prep(dy + (float)h, dx + (float)wcol, id[cc], wg[cc]);
      }
      __builtin_amdgcn_sched_barrier(0);
      float v[4][4];
#pragma unroll
      for (int cc = 0; cc < 4; ++cc) {
        v[cc][0] = cimg[id[cc][0]];
        v[cc][1] = cimg[id[cc][1]];
        v[cc][2] = cimg[id[cc][2]];
        v[cc][3] = cimg[id[cc][3]];
      }
      __builtin_amdgcn_sched_barrier(0);
#pragma unroll
      for (int cc = 0; cc < 4; ++cc)
        cf[g4 * 4 + cc] = v[cc][0] * wg[cc][0] + v[cc][1] * wg[cc][1] +
                          v[cc][2] * wg[cc][2] + v[cc][3] * wg[cc][3];
    }
  }

  float invden = __builtin_amdgcn_rcpf(aff_scale[0] + 1e-8f);
  float t[8];
  float asum = 0.f;
#pragma unroll
  for (int c = 0; c < 8; ++c) {
    float tv = fast_tanh(av[c]) * invden * cf[c];
    t[c] = tv;
    asum += fabsf(tv);
  }
  asum += 1e-4f;
  asum = fmaxf(asum, 1.f);
  float inv_asum = __builtin_amdgcn_rcpf(asum);
  float ssum = 0.f;
#pragma unroll
  for (int c = 0; c < 8; ++c) {
    t[c] *= inv_asum;
    ssum += t[c];
  }

  float v9[9];
#pragma unroll
  for (int c = 0; c < 4; ++c) v9[c] = t[c];
  v9[4] = 1.f - ssum;
#pragma unroll
  for (int c = 4; c < 8; ++c) v9[c + 1] = t[c];

  float mx = v9[0];
#pragma unroll
  for (int i = 1; i < 9; ++i) mx = fmaxf(mx, v9[i]);
  float es = 0.f;
#pragma unroll
  for (int i = 0; i < 9; ++i) {
    v9[i] = __expf(v9[i] - mx);
    es += v9[i];
  }
  float inv = __builtin_amdgcn_rcpf(es);
  float* ob = out_aff + (size_t)b * 9 * HWSZ;
#pragma unroll
  for (int i = 0; i < 9; ++i) ob[i * HWSZ + p] = v9[i] * inv;
}

extern "C" void kernel_launch(void* const* d_in, const int* in_sizes, int n_in,
                              void* d_out, int out_size, void* d_ws,
                              size_t ws_size, hipStream_t stream) {
  const float* guidance = (const float*)d_in[0];
  const float* conf_img = (const float*)d_in[1];
  const float* fea = (const float*)d_in[2];
  const float* Wc = (const float*)d_in[3];
  const float* bc = (const float*)d_in[4];
  const float* ascale = (const float*)d_in[5];

  float* out = (float*)d_out;
  float* out_off = out;                           // (4,18,384,384)
  float* out_aff = out + (size_t)Bn * 18 * HWSZ;  // (4,9,384,384) final output
  // offT3 borrows the aff region of d_out (4.72M floats <= 5.31M available);
  // written by conv, consumed by cw47g before fused3 overwrites the region.
  float* offT3f = out_aff;

  float* affc = (float*)d_ws;                     // 4*8*HW floats
  float* cw4 = affc + (size_t)Bn * 8 * HWSZ;      // 4*4*HW floats
  float* Wt = cw4 + (size_t)Bn * 4 * HWSZ;        // 3456 floats

  wtrans_kernel<<<(COUT * CG * 9 + 255) / 256, 256, 0, stream>>>(Wc, Wt);

  int total = Bn * HWSZ;
  conv_kernel<<<Bn * (HH / TSY) * (WW / TSX), 256, 0, stream>>>(
      guidance, Wt, bc, out_off, affc, offT3f);
  cw47g_kernel<<<total / 256, 256, 0, stream>>>(fea, (const float4*)offT3f,
                                                cw4);
  fused3_kernel<<<total / 256, 256, 0, stream>>>(fea, conf_img, out_off, affc,
                                                 cw4, ascale, out_aff);
}

// Round 15
// 171.639 us; speedup vs baseline: 1.6472x; 1.1721x over previous
//
#include <hip/hip_runtime.h>

constexpr int Bn = 4, CG = 16, HH = 384, WW = 384;
constexpr int HWSZ = HH * WW;  // 147456
constexpr int COUT = 24;
constexpr int TSX = 32, TSY = 16;  // conv tile

// ---------------------------------------------------------------------------
// Weight transpose: Wt[(ic*9+t)*24 + oc] = Wc[(oc*16+ic)*9 + t]
// ---------------------------------------------------------------------------
__global__ void wtrans_kernel(const float* __restrict__ Wc,
                              float* __restrict__ Wt) {
  int i = blockIdx.x * 256 + threadIdx.x;
  if (i < COUT * CG * 9) {
    int oc = i / (CG * 9), rem = i % (CG * 9);
    Wt[rem * COUT + oc] = Wc[i];
  }
}

// ---------------------------------------------------------------------------
// Conv 3x3 SAME 16->24, 32x16 tile, 2 px/thread, ic staged in 2 halves of 8.
// Offsets -> d_out layout; aff channels -> ws planes; c>=4 offsets also
// written as offT3 float4-subplane records (fused transpose).
// ---------------------------------------------------------------------------
__global__ __launch_bounds__(256) void conv_kernel(
    const float* __restrict__ g, const float* __restrict__ Wt,
    const float* __restrict__ bc, float* __restrict__ out_off,
    float* __restrict__ affc, float* __restrict__ offT3f) {
  __shared__ float lds[8 * 18 * 34];  // 19.6 KB
  int bi = blockIdx.x;
  int bx = (bi % (WW / TSX)) * TSX;
  int by = ((bi / (WW / TSX)) % (HH / TSY)) * TSY;
  int b = bi / ((WW / TSX) * (HH / TSY));
  const float* gb = g + (size_t)b * CG * HWSZ;

  int tx = threadIdx.x & 15, ty = threadIdx.x >> 4;
  float acc0[COUT], acc1[COUT];
#pragma unroll
  for (int oc = 0; oc < COUT; ++oc) {
    float bv = bc[oc];
    acc0[oc] = bv;
    acc1[oc] = bv;
  }

  for (int half = 0; half < 2; ++half) {
    if (half) __syncthreads();
    for (int idx = threadIdx.x; idx < 8 * 18 * 34; idx += 256) {
      int icl = idx / 612, rem = idx % 612, y = rem / 34, x = rem % 34;
      int gy = by + y - 1, gx = bx + x - 1;
      float v = (gy >= 0 && gy < HH && gx >= 0 && gx < WW)
                    ? gb[(half * 8 + icl) * HWSZ + gy * WW + gx]
                    : 0.f;
      lds[idx] = v;
    }
    __syncthreads();

    for (int icl = 0; icl < 8; ++icl) {
      int ic = half * 8 + icl;
      const float* base = lds + icl * 612 + ty * 34 + 2 * tx;
      float vals[3][4];
#pragma unroll
      for (int r = 0; r < 3; ++r) {
        float2 v01 = *(const float2*)(base + r * 34);
        float2 v23 = *(const float2*)(base + r * 34 + 2);
        vals[r][0] = v01.x;
        vals[r][1] = v01.y;
        vals[r][2] = v23.x;
        vals[r][3] = v23.y;
      }
#pragma unroll
      for (int r = 0; r < 3; ++r) {
#pragma unroll
        for (int c3 = 0; c3 < 3; ++c3) {
          float va = vals[r][c3], vb = vals[r][c3 + 1];
          const float* wp = Wt + (ic * 9 + r * 3 + c3) * COUT;
#pragma unroll
          for (int oc = 0; oc < COUT; ++oc) {
            acc0[oc] += va * wp[oc];
            acc1[oc] += vb * wp[oc];
          }
        }
      }
    }
  }

  int p = (by + ty) * WW + bx + 2 * tx;
  float* ob = out_off + (size_t)b * 18 * HWSZ;
#pragma unroll
  for (int c = 0; c < 16; ++c) {
    int c18 = (c < 8) ? c : c + 2;
    *(float2*)(ob + c18 * HWSZ + p) = make_float2(acc0[c], acc1[c]);
  }
  *(float2*)(ob + 8 * HWSZ + p) = make_float2(0.f, 0.f);
  *(float2*)(ob + 9 * HWSZ + p) = make_float2(0.f, 0.f);
  float* ab = affc + (size_t)b * 8 * HWSZ;
#pragma unroll
  for (int c = 0; c < 8; ++c)
    *(float2*)(ab + c * HWSZ + p) = make_float2(acc0[16 + c], acc1[16 + c]);

  // Fused offT3 subplane stores (replaces offt3_kernel).
  {
    int X0 = bx + 2 * tx;
    int m = X0 >> 3, j = X0 & 7;
    int Lp = by + ty;
    float* o3b = offT3f + (size_t)b * 16 * 48 * 384 * 4;
#pragma unroll
    for (int pl = 0; pl < 8; ++pl) {
      int cp = pl >> 1, sel = pl & 1;
      int q = sel * 2 + (j >> 2);
      size_t di = ((size_t)(cp * 4 + q) * 48 + m) * 384 + Lp;
      *(float2*)(o3b + di * 4 + (j & 3)) =
          make_float2(acc0[8 + pl], acc1[8 + pl]);
    }
  }
}

// ---------------------------------------------------------------------------
// Bilinear sample, zero padding — identical math to the reference (fallback).
// ---------------------------------------------------------------------------
__device__ __forceinline__ float bilin_zero(const float* __restrict__ img,
                                            float iy, float ix) {
  float y0f = floorf(iy), x0f = floorf(ix);
  float wy1 = iy - y0f, wx1 = ix - x0f;
  int y0 = (int)y0f, x0 = (int)x0f;
  float acc = 0.f;
#pragma unroll
  for (int dy = 0; dy < 2; ++dy) {
    int yc = y0 + dy;
    bool vy = (yc >= 0) && (yc <= HH - 1);
    int yi = min(max(yc, 0), HH - 1);
    float wy = dy ? wy1 : 1.f - wy1;
#pragma unroll
    for (int dx = 0; dx < 2; ++dx) {
      int xc = x0 + dx;
      bool vx = (xc >= 0) && (xc <= WW - 1);
      int xi = min(max(xc, 0), WW - 1);
      float wx = dx ? wx1 : 1.f - wx1;
      float v = img[yi * WW + xi];
      acc += v * (wy * wx) * ((vy && vx) ? 1.f : 0.f);
    }
  }
  return acc;
}

// ---------------------------------------------------------------------------
// cw for c=4..7 with LDS-staged 64x64 image patch (unchanged from round 14).
// ---------------------------------------------------------------------------
__global__ __launch_bounds__(256, 4) void cw47g_kernel(
    const float* __restrict__ fea, const float4* __restrict__ offT3,
    float* __restrict__ cw4) {
  __shared__ float patch[64][68];
  int t = threadIdx.x;
  int lane = t & 63, wv = t >> 6;
  int bi = blockIdx.x;
  int Lblk = bi % 6;  bi /= 6;
  int mblk = bi % 12; bi /= 12;
  int a = bi % 8, b = bi / 8;
  int m = mblk * 4 + wv;
  int Lp = Lblk * 64 + lane;
  int p = a * 18432 + 48 * Lp + m;

  const float* feab = fea + (size_t)b * 8 * HWSZ;
  const float* imgA = feab + (size_t)a * HWSZ;

  int R0 = 32 * mblk - 12;
  R0 = (R0 < 0) ? 0 : (R0 > 320 ? 320 : R0);

  {
    int row = t >> 4, colq = t & 15;
#pragma unroll
    for (int pass = 0; pass < 4; ++pass) {
      int r = pass * 16 + row;
      float4 v = *(const float4*)(imgA + (R0 + r) * WW + R0 + 4 * colq);
      *(float4*)&patch[r][4 * colq] = v;
    }
  }
  __syncthreads();

  float feaj[8];
#pragma unroll
  for (int j = 0; j < 8; ++j) feaj[j] = feab[j * HWSZ + p];

  const float4* o3 = offT3 + (size_t)b * 16 * 48 * 384;
  int recoff = m * 384 + Lp;
  float qf = (float)(8 * m);

#pragma unroll
  for (int cp = 0; cp < 4; ++cp) {
    float4 dy0 = o3[(cp * 4 + 0) * 18432 + recoff];
    float4 dy1 = o3[(cp * 4 + 1) * 18432 + recoff];
    float4 dx0 = o3[(cp * 4 + 2) * 18432 + recoff];
    float4 dx1 = o3[(cp * 4 + 3) * 18432 + recoff];
    float dyv[8] = {dy0.x, dy0.y, dy0.z, dy0.w, dy1.x, dy1.y, dy1.z, dy1.w};
    float dxv[8] = {dx0.x, dx0.y, dx0.z, dx0.w, dx1.x, dx1.y, dx1.z, dx1.w};
    float s = 0.f;
#pragma unroll
    for (int j = 0; j < 8; ++j) {
      float iy = dxv[j] + qf + (float)j;
      float ix = dyv[j] + qf + (float)j;
      float y0f = floorf(iy), x0f = floorf(ix);
      int y0 = (int)y0f, x0 = (int)x0f;
      float fy = iy - y0f, fx = ix - x0f;
      float bv;
      if (y0 >= R0 && y0 <= R0 + 62 && x0 >= R0 && x0 <= R0 + 62) {
        int ry = y0 - R0, rx = x0 - R0;
        float v00 = patch[ry][rx], v01 = patch[ry][rx + 1];
        float v10 = patch[ry + 1][rx], v11 = patch[ry + 1][rx + 1];
        float wy0 = 1.f - fy, wx0 = 1.f - fx;
        bv = v00 * (wy0 * wx0) + v01 * (wy0 * fx) + v10 * (fy * wx0) +
             v11 * (fy * fx);
      } else {
        bv = bilin_zero(imgA, iy, ix);
      }
      s += feaj[j] * bv;
    }
    cw4[((size_t)b * 4 + cp) * HWSZ + p] = s;
  }
}

__device__ __forceinline__ float fast_tanh(float x) {
  float ax = fabsf(x);
  float e = __expf(2.f * ax);  // inf for large ax -> t = 1 (correct limit)
  float t = 1.f - 2.f * __builtin_amdgcn_rcpf(e + 1.f);
  return copysignf(t, x);
}

// ---------------------------------------------------------------------------
// Fused cw03 + epilogue with BOTH gather sets LDS-staged:
//  - fpat: 32x32 imgA patch around the (hr,hr) diagonal (c<4 cos_w gathers)
//  - cpat: 14-row x 384-col conf_img strip around the block's rows
// Out-of-patch samples fall back to global bilin_zero (identical math).
// ---------------------------------------------------------------------------
__global__ __launch_bounds__(256, 4) void fused4_kernel(
    const float* __restrict__ fea, const float* __restrict__ conf_img,
    const float* __restrict__ out_off, const float* __restrict__ affc,
    const float* __restrict__ cw4, const float* __restrict__ aff_scale,
    float* __restrict__ out_aff) {
  __shared__ float fpat[32][36];
  __shared__ float cpat[14][384];
  int t = threadIdx.x;
  unsigned idx0 = blockIdx.x * 256u;
  unsigned b = idx0 / (unsigned)HWSZ;          // block-constant (HWSZ%256==0)
  unsigned pb0 = idx0 % (unsigned)HWSZ;
  unsigned a = (8u * pb0) / (unsigned)HWSZ;    // block-constant (18432%256==0)
  unsigned r0f = 8u * pb0 - a * (unsigned)HWSZ;
  int hrf = (int)(r0f / (unsigned)WW);
  int C0 = hrf - 12;
  C0 = (C0 < 0) ? 0 : (C0 > 352 ? 352 : C0);
  C0 &= ~3;  // 16B-align patch columns
  int h0 = (int)(pb0 / (unsigned)WW);
  int P0r = h0 - 5;
  P0r = (P0r < 0) ? 0 : (P0r > 370 ? 370 : P0r);

  const float* feab = fea + (size_t)b * 8 * HWSZ;
  const float* imgA = feab + (size_t)a * HWSZ;
  const float* cimg = conf_img + (size_t)b * HWSZ;

  // Stage fpat (32x32 from (C0,C0)) and cpat (14x384 from row P0r).
  {
    int rr = t >> 3, cq = t & 7;
    *(float4*)&fpat[rr][4 * cq] =
        *(const float4*)(imgA + (C0 + rr) * WW + C0 + 4 * cq);
  }
  for (int i = t; i < 14 * 96; i += 256) {
    int rr = i / 96, cq = i % 96;
    *(float4*)&cpat[rr][4 * cq] =
        *(const float4*)(cimg + (P0r + rr) * WW + 4 * cq);
  }
  __syncthreads();

  unsigned p = pb0 + t;
  unsigned h = p / (unsigned)WW, wcol = p % (unsigned)WW;
  unsigned r0 = 8u * p - a * (unsigned)HWSZ;
  unsigned hr = r0 / (unsigned)WW;
  float cb = (float)hr;

  float feaj[8];
#pragma unroll
  for (int j = 0; j < 8; ++j) feaj[j] = feab[j * HWSZ + p];

  const float* offb = out_off + (size_t)b * 18 * HWSZ;
  const float* ab = affc + (size_t)b * 8 * HWSZ;

  float av[8];
#pragma unroll
  for (int c = 0; c < 4; ++c) {
    const float* dyp = offb + (2 * c) * HWSZ + r0;
    const float* dxp = offb + (2 * c + 1) * HWSZ + r0;
    float4 dy0 = *(const float4*)dyp, dy1 = *(const float4*)(dyp + 4);
    float4 dx0 = *(const float4*)dxp, dx1 = *(const float4*)(dxp + 4);
    float dyv[8] = {dy0.x, dy0.y, dy0.z, dy0.w, dy1.x, dy1.y, dy1.z, dy1.w};
    float dxv[8] = {dx0.x, dx0.y, dx0.z, dx0.w, dx1.x, dx1.y, dx1.z, dx1.w};
    float s = 0.f;
#pragma unroll
    for (int j = 0; j < 8; ++j) {
      float iy = dxv[j] + cb, ix = dyv[j] + cb;
      float y0f = floorf(iy), x0f = floorf(ix);
      int y0 = (int)y0f, x0 = (int)x0f;
      float fy = iy - y0f, fx = ix - x0f;
      float bv;
      if (y0 >= C0 && y0 <= C0 + 30 && x0 >= C0 && x0 <= C0 + 30) {
        int ry = y0 - C0, rx = x0 - C0;
        float wy0 = 1.f - fy, wx0 = 1.f - fx;
        bv = fpat[ry][rx] * (wy0 * wx0) + fpat[ry][rx + 1] * (wy0 * fx) +
             fpat[ry + 1][rx] * (fy * wx0) + fpat[ry + 1][rx + 1] * (fy * fx);
      } else {
        bv = bilin_zero(imgA, iy, ix);
      }
      s += feaj[j] * bv;
    }
    av[c] = ab[c * HWSZ + p] * s;
  }
#pragma unroll
  for (int c = 4; c < 8; ++c)
    av[c] = ab[c * HWSZ + p] * cw4[((size_t)b * 4 + (c - 4)) * HWSZ + p];

  float cf[8];
#pragma unroll
  for (int c = 0; c < 8; ++c) {
    int chy = (c < 4) ? 2 * c : 2 * c + 2;
    float dy = offb[chy * HWSZ + p];
    float dx = offb[(chy + 1) * HWSZ + p];
    float iy = dy + (float)h, ix = dx + (float)wcol;
    float y0f = floorf(iy), x0f = floorf(ix);
    int y0 = (int)y0f, x0 = (int)x0f;
    float fy = iy - y0f, fx = ix - x0f;
    if (y0 >= P0r && y0 <= P0r + 12 && x0 >= 0 && x0 <= 382) {
      int ry = y0 - P0r;
      float wy0 = 1.f - fy, wx0 = 1.f - fx;
      cf[c] = cpat[ry][x0] * (wy0 * wx0) + cpat[ry][x0 + 1] * (wy0 * fx) +
              cpat[ry + 1][x0] * (fy * wx0) +
              cpat[ry + 1][x0 + 1] * (fy * fx);
    } else {
      cf[c] = bilin_zero(cimg, iy, ix);
    }
  }

  float invden = __builtin_amdgcn_rcpf(aff_scale[0] + 1e-8f);
  float tv8[8];
  float asum = 0.f;
#pragma unroll
  for (int c = 0; c < 8; ++c) {
    float tv = fast_tanh(av[c]) * invden * cf[c];
    tv8[c] = tv;
    asum += fabsf(tv);
  }
  asum += 1e-4f;
  asum = fmaxf(asum, 1.f);
  float inv_asum = __builtin_amdgcn_rcpf(asum);
  float ssum = 0.f;
#pragma unroll
  for (int c = 0; c < 8; ++c) {
    tv8[c] *= inv_asum;
    ssum += tv8[c];
  }

  float v9[9];
#pragma unroll
  for (int c = 0; c < 4; ++c) v9[c] = tv8[c];
  v9[4] = 1.f - ssum;
#pragma unroll
  for (int c = 4; c < 8; ++c) v9[c + 1] = tv8[c];

  float mx = v9[0];
#pragma unroll
  for (int i = 1; i < 9; ++i) mx = fmaxf(mx, v9[i]);
  float es = 0.f;
#pragma unroll
  for (int i = 0; i < 9; ++i) {
    v9[i] = __expf(v9[i] - mx);
    es += v9[i];
  }
  float inv = __builtin_amdgcn_rcpf(es);
  float* ob = out_aff + (size_t)b * 9 * HWSZ;
#pragma unroll
  for (int i = 0; i < 9; ++i) ob[i * HWSZ + p] = v9[i] * inv;
}

extern "C" void kernel_launch(void* const* d_in, const int* in_sizes, int n_in,
                              void* d_out, int out_size, void* d_ws,
                              size_t ws_size, hipStream_t stream) {
  const float* guidance = (const float*)d_in[0];
  const float* conf_img = (const float*)d_in[1];
  const float* fea = (const float*)d_in[2];
  const float* Wc = (const float*)d_in[3];
  const float* bc = (const float*)d_in[4];
  const float* ascale = (const float*)d_in[5];

  float* out = (float*)d_out;
  float* out_off = out;                           // (4,18,384,384)
  float* out_aff = out + (size_t)Bn * 18 * HWSZ;  // (4,9,384,384) final output
  // offT3 borrows the aff region of d_out; written by conv, consumed by
  // cw47g before fused4 overwrites the region. 16B-aligned.
  float* offT3f = out_aff;

  float* affc = (float*)d_ws;                     // 4*8*HW floats
  float* cw4 = affc + (size_t)Bn * 8 * HWSZ;      // 4*4*HW floats
  float* Wt = cw4 + (size_t)Bn * 4 * HWSZ;        // 3456 floats

  wtrans_kernel<<<(COUT * CG * 9 + 255) / 256, 256, 0, stream>>>(Wc, Wt);

  int total = Bn * HWSZ;
  conv_kernel<<<Bn * (HH / TSY) * (WW / TSX), 256, 0, stream>>>(
      guidance, Wt, bc, out_off, affc, offT3f);
  cw47g_kernel<<<total / 256, 256, 0, stream>>>(fea, (const float4*)offT3f,
                                                cw4);
  fused4_kernel<<<total / 256, 256, 0, stream>>>(fea, conf_img, out_off, affc,
                                                 cw4, ascale, out_aff);
}

// Round 16
// 167.268 us; speedup vs baseline: 1.6902x; 1.0261x over previous
//
#include <hip/hip_runtime.h>

constexpr int Bn = 4, CG = 16, HH = 384, WW = 384;
constexpr int HWSZ = HH * WW;  // 147456
constexpr int COUT = 24;
constexpr int TSX = 32, TSY = 16;  // conv tile

// ---------------------------------------------------------------------------
// Weight transpose: Wt[(ic*9+t)*24 + oc] = Wc[(oc*16+ic)*9 + t]
// ---------------------------------------------------------------------------
__global__ void wtrans_kernel(const float* __restrict__ Wc,
                              float* __restrict__ Wt) {
  int i = blockIdx.x * 256 + threadIdx.x;
  if (i < COUT * CG * 9) {
    int oc = i / (CG * 9), rem = i % (CG * 9);
    Wt[rem * COUT + oc] = Wc[i];
  }
}

// ---------------------------------------------------------------------------
// Conv 3x3 SAME 16->24, 32x16 tile, 2 px/thread, ic staged in 2 halves of 8.
// (Round-13 version: NO offT3 scatter stores — those cost +24 us in conv.)
// ---------------------------------------------------------------------------
__global__ __launch_bounds__(256) void conv_kernel(
    const float* __restrict__ g, const float* __restrict__ Wt,
    const float* __restrict__ bc, float* __restrict__ out_off,
    float* __restrict__ affc) {
  __shared__ float lds[8 * 18 * 34];  // 19.6 KB
  int bi = blockIdx.x;
  int bx = (bi % (WW / TSX)) * TSX;
  int by = ((bi / (WW / TSX)) % (HH / TSY)) * TSY;
  int b = bi / ((WW / TSX) * (HH / TSY));
  const float* gb = g + (size_t)b * CG * HWSZ;

  int tx = threadIdx.x & 15, ty = threadIdx.x >> 4;
  float acc0[COUT], acc1[COUT];
#pragma unroll
  for (int oc = 0; oc < COUT; ++oc) {
    float bv = bc[oc];
    acc0[oc] = bv;
    acc1[oc] = bv;
  }

  for (int half = 0; half < 2; ++half) {
    if (half) __syncthreads();
    for (int idx = threadIdx.x; idx < 8 * 18 * 34; idx += 256) {
      int icl = idx / 612, rem = idx % 612, y = rem / 34, x = rem % 34;
      int gy = by + y - 1, gx = bx + x - 1;
      float v = (gy >= 0 && gy < HH && gx >= 0 && gx < WW)
                    ? gb[(half * 8 + icl) * HWSZ + gy * WW + gx]
                    : 0.f;
      lds[idx] = v;
    }
    __syncthreads();

    for (int icl = 0; icl < 8; ++icl) {
      int ic = half * 8 + icl;
      const float* base = lds + icl * 612 + ty * 34 + 2 * tx;
      float vals[3][4];
#pragma unroll
      for (int r = 0; r < 3; ++r) {
        float2 v01 = *(const float2*)(base + r * 34);
        float2 v23 = *(const float2*)(base + r * 34 + 2);
        vals[r][0] = v01.x;
        vals[r][1] = v01.y;
        vals[r][2] = v23.x;
        vals[r][3] = v23.y;
      }
#pragma unroll
      for (int r = 0; r < 3; ++r) {
#pragma unroll
        for (int c3 = 0; c3 < 3; ++c3) {
          float va = vals[r][c3], vb = vals[r][c3 + 1];
          const float* wp = Wt + (ic * 9 + r * 3 + c3) * COUT;
#pragma unroll
          for (int oc = 0; oc < COUT; ++oc) {
            acc0[oc] += va * wp[oc];
            acc1[oc] += vb * wp[oc];
          }
        }
      }
    }
  }

  int p = (by + ty) * WW + bx + 2 * tx;
  float* ob = out_off + (size_t)b * 18 * HWSZ;
#pragma unroll
  for (int c = 0; c < 16; ++c) {
    int c18 = (c < 8) ? c : c + 2;
    *(float2*)(ob + c18 * HWSZ + p) = make_float2(acc0[c], acc1[c]);
  }
  *(float2*)(ob + 8 * HWSZ + p) = make_float2(0.f, 0.f);
  *(float2*)(ob + 9 * HWSZ + p) = make_float2(0.f, 0.f);
  float* ab = affc + (size_t)b * 8 * HWSZ;
#pragma unroll
  for (int c = 0; c < 8; ++c)
    *(float2*)(ab + c * HWSZ + p) = make_float2(acc0[16 + c], acc1[16 + c]);
}

// ---------------------------------------------------------------------------
// offT3: the c>=4 offset planes (out ch 10..17) as 16 float4 SUBPLANES
// (round-13 version, restored):
// offT3[((b*16 + cp*4 + q)*48 + m)*384 + Lp], q=0: dy j0-3, 1: dy j4-7,
// 2: dx j0-3, 3: dx j4-7; source elem = ch[Lp*384 + 8m + j].
// ---------------------------------------------------------------------------
__global__ __launch_bounds__(256) void offt3_kernel(
    const float* __restrict__ out_off, float4* __restrict__ offT3) {
  __shared__ float lds[64][68];
  int bi = blockIdx.x;
  int vt = bi % 6;  bi /= 6;
  int lt = bi % 6;  bi /= 6;
  int pl = bi % 8;
  int b = bi / 8;
  int cp = pl >> 1, sel = pl & 1;
  const float* src =
      out_off + ((size_t)b * 18 + 10 + pl) * HWSZ + (lt * 64) * WW + vt * 64;
  int t = threadIdx.x;
#pragma unroll
  for (int i = 0; i < 4; ++i) {
    int flat = i * 1024 + t * 4;
    int row = flat >> 6, col = flat & 63;
    *(float4*)&lds[row][col] = *(const float4*)(src + row * WW + col);
  }
  __syncthreads();
#pragma unroll
  for (int i = 0; i < 4; ++i) {
    int f4 = i * 256 + t;
    int Lpl = f4 & 63;
    int ml = (f4 >> 6) & 7;
    int h = f4 >> 9;
    float4 v = *(const float4*)&lds[Lpl][8 * ml + 4 * h];
    int q = sel * 2 + h;
    size_t di = ((size_t)(b * 16 + cp * 4 + q) * 48 + (vt * 8 + ml)) * 384 +
                (lt * 64 + Lpl);
    offT3[di] = v;
  }
}

// ---------------------------------------------------------------------------
// Bilinear sample, zero padding — identical math to the reference (fallback).
// ---------------------------------------------------------------------------
__device__ __forceinline__ float bilin_zero(const float* __restrict__ img,
                                            float iy, float ix) {
  float y0f = floorf(iy), x0f = floorf(ix);
  float wy1 = iy - y0f, wx1 = ix - x0f;
  int y0 = (int)y0f, x0 = (int)x0f;
  float acc = 0.f;
#pragma unroll
  for (int dy = 0; dy < 2; ++dy) {
    int yc = y0 + dy;
    bool vy = (yc >= 0) && (yc <= HH - 1);
    int yi = min(max(yc, 0), HH - 1);
    float wy = dy ? wy1 : 1.f - wy1;
#pragma unroll
    for (int dx = 0; dx < 2; ++dx) {
      int xc = x0 + dx;
      bool vx = (xc >= 0) && (xc <= WW - 1);
      int xi = min(max(xc, 0), WW - 1);
      float wx = dx ? wx1 : 1.f - wx1;
      float v = img[yi * WW + xi];
      acc += v * (wy * wx) * ((vy && vx) ? 1.f : 0.f);
    }
  }
  return acc;
}

// ---------------------------------------------------------------------------
// cw for c=4..7: LDS patch for gathers (round 14) + cooperative LDS staging
// of fea operands and cw4 results (round 8's structure — viable now that the
// gathers no longer flood the VMEM path).
// ---------------------------------------------------------------------------
__global__ __launch_bounds__(256, 4) void cw47h_kernel(
    const float* __restrict__ fea, const float4* __restrict__ offT3,
    float* __restrict__ cw4) {
  __shared__ float patch[64][68];   // 17.4 KB
  __shared__ float sfea[8][64][5];  // 10.2 KB
  __shared__ float scw[4][64][5];   //  5.1 KB
  int t = threadIdx.x;
  int lane = t & 63, wv = t >> 6;
  int bi = blockIdx.x;
  int Lblk = bi % 6;  bi /= 6;
  int mblk = bi % 12; bi /= 12;
  int a = bi % 8, b = bi / 8;
  int m = mblk * 4 + wv;

  const float* feab = fea + (size_t)b * 8 * HWSZ;
  const float* imgA = feab + (size_t)a * HWSZ;
  int p_base = a * 18432 + 48 * (Lblk * 64) + mblk * 4;  // + 48*Lpl + k

  int R0 = 32 * mblk - 12;
  R0 = (R0 < 0) ? 0 : (R0 > 320 ? 320 : R0);

  // Cooperative fea staging: 512 float4 runs (8 j x 64 Lpl), 2 per thread.
#pragma unroll
  for (int i = 0; i < 2; ++i) {
    int L = i * 256 + t;
    int j = L >> 6, Lpl = L & 63;
    float4 v = *(const float4*)(feab + (size_t)j * HWSZ + p_base + 48 * Lpl);
    sfea[j][Lpl][0] = v.x;
    sfea[j][Lpl][1] = v.y;
    sfea[j][Lpl][2] = v.z;
    sfea[j][Lpl][3] = v.w;
  }
  // Image patch staging (64x64 from (R0,R0)).
  {
    int row = t >> 4, colq = t & 15;
#pragma unroll
    for (int pass = 0; pass < 4; ++pass) {
      int r = pass * 16 + row;
      float4 v = *(const float4*)(imgA + (R0 + r) * WW + R0 + 4 * colq);
      *(float4*)&patch[r][4 * colq] = v;
    }
  }
  __syncthreads();

  float feaj[8];
#pragma unroll
  for (int j = 0; j < 8; ++j) feaj[j] = sfea[j][lane][wv];

  const float4* o3 = offT3 + (size_t)b * 16 * 48 * 384;
  int recoff = m * 384 + (Lblk * 64 + lane);
  float qf = (float)(8 * m);

#pragma unroll
  for (int cp = 0; cp < 4; ++cp) {
    float4 dy0 = o3[(cp * 4 + 0) * 18432 + recoff];
    float4 dy1 = o3[(cp * 4 + 1) * 18432 + recoff];
    float4 dx0 = o3[(cp * 4 + 2) * 18432 + recoff];
    float4 dx1 = o3[(cp * 4 + 3) * 18432 + recoff];
    float dyv[8] = {dy0.x, dy0.y, dy0.z, dy0.w, dy1.x, dy1.y, dy1.z, dy1.w};
    float dxv[8] = {dx0.x, dx0.y, dx0.z, dx0.w, dx1.x, dx1.y, dx1.z, dx1.w};
    float s = 0.f;
#pragma unroll
    for (int j = 0; j < 8; ++j) {
      float iy = dxv[j] + qf + (float)j;
      float ix = dyv[j] + qf + (float)j;
      float y0f = floorf(iy), x0f = floorf(ix);
      int y0 = (int)y0f, x0 = (int)x0f;
      float fy = iy - y0f, fx = ix - x0f;
      float bv;
      if (y0 >= R0 && y0 <= R0 + 62 && x0 >= R0 && x0 <= R0 + 62) {
        int ry = y0 - R0, rx = x0 - R0;
        float v00 = patch[ry][rx], v01 = patch[ry][rx + 1];
        float v10 = patch[ry + 1][rx], v11 = patch[ry + 1][rx + 1];
        float wy0 = 1.f - fy, wx0 = 1.f - fx;
        bv = v00 * (wy0 * wx0) + v01 * (wy0 * fx) + v10 * (fy * wx0) +
             v11 * (fy * fx);
      } else {
        bv = bilin_zero(imgA, iy, ix);
      }
      s += feaj[j] * bv;
    }
    scw[cp][lane][wv] = s;
  }
  __syncthreads();

  // Cooperative cw4 write: 256 float4 runs (4 cp x 64 Lpl), 1 per thread.
  {
    int cp = t >> 6, Lpl = t & 63;
    float4 v;
    v.x = scw[cp][Lpl][0];
    v.y = scw[cp][Lpl][1];
    v.z = scw[cp][Lpl][2];
    v.w = scw[cp][Lpl][3];
    *(float4*)(cw4 + (size_t)(b * 4 + cp) * HWSZ + p_base + 48 * Lpl) = v;
  }
}

__device__ __forceinline__ float fast_tanh(float x) {
  float ax = fabsf(x);
  float e = __expf(2.f * ax);  // inf for large ax -> t = 1 (correct limit)
  float t = 1.f - 2.f * __builtin_amdgcn_rcpf(e + 1.f);
  return copysignf(t, x);
}

// ---------------------------------------------------------------------------
// Fused cw03 + epilogue with both gather sets LDS-staged; p-local operand
// loads hoisted above staging so HBM latency overlaps the LDS fill.
// ---------------------------------------------------------------------------
__global__ __launch_bounds__(256, 4) void fused4_kernel(
    const float* __restrict__ fea, const float* __restrict__ conf_img,
    const float* __restrict__ out_off, const float* __restrict__ affc,
    const float* __restrict__ cw4, const float* __restrict__ aff_scale,
    float* __restrict__ out_aff) {
  __shared__ float fpat[32][36];
  __shared__ float cpat[14][384];
  int t = threadIdx.x;
  unsigned idx0 = blockIdx.x * 256u;
  unsigned b = idx0 / (unsigned)HWSZ;
  unsigned pb0 = idx0 % (unsigned)HWSZ;
  unsigned a = (8u * pb0) / (unsigned)HWSZ;
  unsigned r0f = 8u * pb0 - a * (unsigned)HWSZ;
  int hrf = (int)(r0f / (unsigned)WW);
  int C0 = hrf - 12;
  C0 = (C0 < 0) ? 0 : (C0 > 352 ? 352 : C0);
  C0 &= ~3;
  int h0 = (int)(pb0 / (unsigned)WW);
  int P0r = h0 - 5;
  P0r = (P0r < 0) ? 0 : (P0r > 370 ? 370 : P0r);

  const float* feab = fea + (size_t)b * 8 * HWSZ;
  const float* imgA = feab + (size_t)a * HWSZ;
  const float* cimg = conf_img + (size_t)b * HWSZ;

  unsigned p = pb0 + t;
  const float* offb = out_off + (size_t)b * 18 * HWSZ;
  const float* ab = affc + (size_t)b * 8 * HWSZ;

  // Hoisted p-local loads (in flight during LDS staging below).
  float feaj[8];
#pragma unroll
  for (int j = 0; j < 8; ++j) feaj[j] = feab[j * HWSZ + p];
  float abv[8];
#pragma unroll
  for (int c = 0; c < 8; ++c) abv[c] = ab[c * HWSZ + p];
  float cw4v[4];
#pragma unroll
  for (int c = 0; c < 4; ++c) cw4v[c] = cw4[((size_t)b * 4 + c) * HWSZ + p];

  // Stage fpat (32x32 from (C0,C0)) and cpat (14x384 from row P0r).
  {
    int rr = t >> 3, cq = t & 7;
    *(float4*)&fpat[rr][4 * cq] =
        *(const float4*)(imgA + (C0 + rr) * WW + C0 + 4 * cq);
  }
  for (int i = t; i < 14 * 96; i += 256) {
    int rr = i / 96, cq = i % 96;
    *(float4*)&cpat[rr][4 * cq] =
        *(const float4*)(cimg + (P0r + rr) * WW + 4 * cq);
  }
  __syncthreads();

  unsigned h = p / (unsigned)WW, wcol = p % (unsigned)WW;
  unsigned r0 = 8u * p - a * (unsigned)HWSZ;
  unsigned hr = r0 / (unsigned)WW;
  float cb = (float)hr;

  float av[8];
#pragma unroll
  for (int c = 0; c < 4; ++c) {
    const float* dyp = offb + (2 * c) * HWSZ + r0;
    const float* dxp = offb + (2 * c + 1) * HWSZ + r0;
    float4 dy0 = *(const float4*)dyp, dy1 = *(const float4*)(dyp + 4);
    float4 dx0 = *(const float4*)dxp, dx1 = *(const float4*)(dxp + 4);
    float dyv[8] = {dy0.x, dy0.y, dy0.z, dy0.w, dy1.x, dy1.y, dy1.z, dy1.w};
    float dxv[8] = {dx0.x, dx0.y, dx0.z, dx0.w, dx1.x, dx1.y, dx1.z, dx1.w};
    float s = 0.f;
#pragma unroll
    for (int j = 0; j < 8; ++j) {
      float iy = dxv[j] + cb, ix = dyv[j] + cb;
      float y0f = floorf(iy), x0f = floorf(ix);
      int y0 = (int)y0f, x0 = (int)x0f;
      float fy = iy - y0f, fx = ix - x0f;
      float bv;
      if (y0 >= C0 && y0 <= C0 + 30 && x0 >= C0 && x0 <= C0 + 30) {
        int ry = y0 - C0, rx = x0 - C0;
        float wy0 = 1.f - fy, wx0 = 1.f - fx;
        bv = fpat[ry][rx] * (wy0 * wx0) + fpat[ry][rx + 1] * (wy0 * fx) +
             fpat[ry + 1][rx] * (fy * wx0) + fpat[ry + 1][rx + 1] * (fy * fx);
      } else {
        bv = bilin_zero(imgA, iy, ix);
      }
      s += feaj[j] * bv;
    }
    av[c] = abv[c] * s;
  }
#pragma unroll
  for (int c = 4; c < 8; ++c) av[c] = abv[c] * cw4v[c - 4];

  float cf[8];
#pragma unroll
  for (int c = 0; c < 8; ++c) {
    int chy = (c < 4) ? 2 * c : 2 * c + 2;
    float dy = offb[chy * HWSZ + p];
    float dx = offb[(chy + 1) * HWSZ + p];
    float iy = dy + (float)h, ix = dx + (float)wcol;
    float y0f = floorf(iy), x0f = floorf(ix);
    int y0 = (int)y0f, x0 = (int)x0f;
    float fy = iy - y0f, fx = ix - x0f;
    if (y0 >= P0r && y0 <= P0r + 12 && x0 >= 0 && x0 <= 382) {
      int ry = y0 - P0r;
      float wy0 = 1.f - fy, wx0 = 1.f - fx;
      cf[c] = cpat[ry][x0] * (wy0 * wx0) + cpat[ry][x0 + 1] * (wy0 * fx) +
              cpat[ry + 1][x0] * (fy * wx0) +
              cpat[ry + 1][x0 + 1] * (fy * fx);
    } else {
      cf[c] = bilin_zero(cimg, iy, ix);
    }
  }

  float invden = __builtin_amdgcn_rcpf(aff_scale[0] + 1e-8f);
  float tv8[8];
  float asum = 0.f;
#pragma unroll
  for (int c = 0; c < 8; ++c) {
    float tv = fast_tanh(av[c]) * invden * cf[c];
    tv8[c] = tv;
    asum += fabsf(tv);
  }
  asum += 1e-4f;
  asum = fmaxf(asum, 1.f);
  float inv_asum = __builtin_amdgcn_rcpf(asum);
  float ssum = 0.f;
#pragma unroll
  for (int c = 0; c < 8; ++c) {
    tv8[c] *= inv_asum;
    ssum += tv8[c];
  }

  float v9[9];
#pragma unroll
  for (int c = 0; c < 4; ++c) v9[c] = tv8[c];
  v9[4] = 1.f - ssum;
#pragma unroll
  for (int c = 4; c < 8; ++c) v9[c + 1] = tv8[c];

  float mx = v9[0];
#pragma unroll
  for (int i = 1; i < 9; ++i) mx = fmaxf(mx, v9[i]);
  float es = 0.f;
#pragma unroll
  for (int i = 0; i < 9; ++i) {
    v9[i] = __expf(v9[i] - mx);
    es += v9[i];
  }
  float inv = __builtin_amdgcn_rcpf(es);
  float* ob = out_aff + (size_t)b * 9 * HWSZ;
#pragma unroll
  for (int i = 0; i < 9; ++i) ob[i * HWSZ + p] = v9[i] * inv;
}

extern "C" void kernel_launch(void* const* d_in, const int* in_sizes, int n_in,
                              void* d_out, int out_size, void* d_ws,
                              size_t ws_size, hipStream_t stream) {
  const float* guidance = (const float*)d_in[0];
  const float* conf_img = (const float*)d_in[1];
  const float* fea = (const float*)d_in[2];
  const float* Wc = (const float*)d_in[3];
  const float* bc = (const float*)d_in[4];
  const float* ascale = (const float*)d_in[5];

  float* out = (float*)d_out;
  float* out_off = out;                           // (4,18,384,384)
  float* out_aff = out + (size_t)Bn * 18 * HWSZ;  // (4,9,384,384) final output
  // offT3 borrows the aff region of d_out; written by offt3, consumed by
  // cw47h before fused4 overwrites the region. 16B-aligned.
  float4* offT3 = (float4*)out_aff;

  float* affc = (float*)d_ws;                     // 4*8*HW floats
  float* cw4 = affc + (size_t)Bn * 8 * HWSZ;      // 4*4*HW floats
  float* Wt = cw4 + (size_t)Bn * 4 * HWSZ;        // 3456 floats

  wtrans_kernel<<<(COUT * CG * 9 + 255) / 256, 256, 0, stream>>>(Wc, Wt);

  int total = Bn * HWSZ;
  conv_kernel<<<Bn * (HH / TSY) * (WW / TSX), 256, 0, stream>>>(guidance, Wt,
                                                                bc, out_off,
                                                                affc);
  offt3_kernel<<<Bn * 8 * 6 * 6, 256, 0, stream>>>(out_off, offT3);
  cw47h_kernel<<<total / 256, 256, 0, stream>>>(fea, offT3, cw4);
  fused4_kernel<<<total / 256, 256, 0, stream>>>(fea, conf_img, out_off, affc,
                                                 cw4, ascale, out_aff);
}